// Round 5
// baseline (2830.707 us; speedup 1.0000x reference)
//
#include <hip/hip_runtime.h>
#include <hip/hip_bf16.h>

typedef float  v4f __attribute__((ext_vector_type(4)));
typedef short  v8s __attribute__((ext_vector_type(8)));
typedef int    v4i __attribute__((ext_vector_type(4)));

#define DEV static __device__ __forceinline__

DEV float bf2f(unsigned short u) {
    union { unsigned int i; float f; } x; x.i = ((unsigned int)u) << 16; return x.f;
}
DEV unsigned short f2bf(float f) {
    union { float f; unsigned int i; } x; x.f = f;
    unsigned int r = x.i + 0x7fff + ((x.i >> 16) & 1);
    return (unsigned short)(r >> 16);
}
DEV float sigm(float x) { return 1.f / (1.f + __expf(-x)); }

DEV v4i pack8(const float* f) {
    v4i o;
#pragma unroll
    for (int q = 0; q < 4; ++q)
        ((unsigned int*)&o)[q] = (unsigned int)f2bf(f[2 * q]) |
                                 ((unsigned int)f2bf(f[2 * q + 1]) << 16);
    return o;
}
DEV float lo16(unsigned int x) { union { unsigned int i; float f; } u; u.i = x << 16; return u.f; }
DEV float hi16(unsigned int x) { union { unsigned int i; float f; } u; u.i = x & 0xffff0000u; return u.f; }

// Coherent (agent-scope, relaxed) 4B loads/stores: serviced at the MALL
// coherence point, bypassing the non-coherent per-XCD L2s. Used ONLY for the
// two buffers that cross blocks inside the persistent loop (z, h). This lets
// the grid barrier drop release/acquire fences entirely -- rounds 2-4 showed
// the per-barrier buffer_wbl2 (256x) + buffer_inv (256x, wipes L2 -> 21MB/step
// HBM refetch of weights) cost ~50us/barrier regardless of spin mechanism.
DEV unsigned int cload(const unsigned int* p) {
    return __hip_atomic_load(p, __ATOMIC_RELAXED, __HIP_MEMORY_SCOPE_AGENT);
}
DEV void cstoreu(unsigned int* p, unsigned int v) {
    __hip_atomic_store(p, v, __ATOMIC_RELAXED, __HIP_MEMORY_SCOPE_AGENT);
}
DEV v4i cload4(const unsigned short* p) {
    const unsigned int* q = (const unsigned int*)p;
    v4i r;
    ((unsigned int*)&r)[0] = cload(q);
    ((unsigned int*)&r)[1] = cload(q + 1);
    ((unsigned int*)&r)[2] = cload(q + 2);
    ((unsigned int*)&r)[3] = cload(q + 3);
    return r;
}
DEV void cstore4(unsigned short* p, v4i v) {
    unsigned int* q = (unsigned int*)p;
    cstoreu(q,     ((unsigned int*)&v)[0]);
    cstoreu(q + 1, ((unsigned int*)&v)[1]);
    cstoreu(q + 2, ((unsigned int*)&v)[2]);
    cstoreu(q + 3, ((unsigned int*)&v)[3]);
}

// Fence-free grid barrier: __syncthreads() already drains all waves' vmem
// (compiler emits s_waitcnt vmcnt(0) before s_barrier), so every coherent
// store is acked at the MALL before arrival. Relaxed RMW arrive + relaxed RMW
// spin (RMWs are always serviced at the coherence point). No wbl2, no inv.
DEV void gbar(int* cnt, int target) {
    __syncthreads();
    if (threadIdx.x == 0) {
        __hip_atomic_fetch_add(cnt, 1, __ATOMIC_RELAXED, __HIP_MEMORY_SCOPE_AGENT);
        if (__hip_atomic_fetch_add(cnt, 0, __ATOMIC_RELAXED, __HIP_MEMORY_SCOPE_AGENT) < target) {
            __builtin_amdgcn_s_sleep(1);
            while (__hip_atomic_fetch_add(cnt, 0, __ATOMIC_RELAXED, __HIP_MEMORY_SCOPE_AGENT) < target)
                __builtin_amdgcn_s_sleep(32);
        }
        asm volatile("" ::: "memory");   // compiler fence: no hoisting of reads
    }
    __syncthreads();
}

// ---------------------------------------------------------------------------
// uber_init: 8 elements per thread, 16B loads + 16B stores.
// ---------------------------------------------------------------------------
__global__ __launch_bounds__(256) void uber_init(
    const float* __restrict__ Wih, const float* __restrict__ Whh,
    const float* __restrict__ bih, const float* __restrict__ bhh,
    const float* __restrict__ WoutF, const float* __restrict__ WeattF,
    const float* __restrict__ WdattF, const float* __restrict__ Wh0F,
    const float* __restrict__ Wc0F, const float* __restrict__ enc,
    const int* __restrict__ caps, const float* __restrict__ embed,
    unsigned short* __restrict__ Wz, unsigned short* __restrict__ Woutb,
    unsigned short* __restrict__ Weattb, unsigned short* __restrict__ Wdattb,
    unsigned short* __restrict__ Wh0b, unsigned short* __restrict__ Wc0b,
    unsigned short* __restrict__ encb, unsigned short* __restrict__ embb,
    unsigned short* __restrict__ meanb, float* __restrict__ bz)
{
    const int i = (blockIdx.x * 256 + threadIdx.x) * 8;
    float f[8];
    if (i < 11534336) {                       // Wz = [W_ih | W_hh] rows of 2816
        int n = i / 2816, k = i - n * 2816;
        const float* src = (k < 1792) ? &Wih[n * 1792 + k] : &Whh[n * 1024 + (k - 1792)];
        *(v4f*)&f[0] = *(const v4f*)src; *(v4f*)&f[4] = *(const v4f*)(src + 4);
        *(v4i*)&Wz[i] = pack8(f);
    } else if (i < 21774336) {                // W_out
        int j = i - 11534336;
        *(v4f*)&f[0] = *(const v4f*)&WoutF[j]; *(v4f*)&f[4] = *(const v4f*)&WoutF[j + 4];
        *(v4i*)&Woutb[j] = pack8(f);
    } else if (i < 22429696) {                // W_eatt
        int j = i - 21774336;
        *(v4f*)&f[0] = *(const v4f*)&WeattF[j]; *(v4f*)&f[4] = *(const v4f*)&WeattF[j + 4];
        *(v4i*)&Weattb[j] = pack8(f);
    } else if (i < 22953984) {                // W_datt
        int j = i - 22429696;
        *(v4f*)&f[0] = *(const v4f*)&WdattF[j]; *(v4f*)&f[4] = *(const v4f*)&WdattF[j + 4];
        *(v4i*)&Wdattb[j] = pack8(f);
    } else if (i < 24264704) {                // W_h0
        int j = i - 22953984;
        *(v4f*)&f[0] = *(const v4f*)&Wh0F[j]; *(v4f*)&f[4] = *(const v4f*)&Wh0F[j + 4];
        *(v4i*)&Wh0b[j] = pack8(f);
    } else if (i < 25575424) {                // W_c0
        int j = i - 24264704;
        *(v4f*)&f[0] = *(const v4f*)&Wc0F[j]; *(v4f*)&f[4] = *(const v4f*)&Wc0F[j + 4];
        *(v4i*)&Wc0b[j] = pack8(f);
    } else if (i < 29589504) {                // encoder_out
        int j = i - 25575424;
        *(v4f*)&f[0] = *(const v4f*)&enc[j]; *(v4f*)&f[4] = *(const v4f*)&enc[j + 4];
        *(v4i*)&encb[j] = pack8(f);
    } else if (i < 30375936) {                // emb gather (t < 24 only)
        int j = i - 29589504;
        int b = j / 12288, r = j - b * 12288, t = r / 512, e = r - t * 512;
        const float* src = &embed[caps[b * 25 + t] * 512 + e];
        *(v4f*)&f[0] = *(const v4f*)src; *(v4f*)&f[4] = *(const v4f*)(src + 4);
        *(v4i*)&embb[j] = pack8(f);
    } else if (i < 30457856) {                // mean over P=49
        int j = i - 30375936;
        int b = j / 1280, c = j - b * 1280;
#pragma unroll
        for (int q = 0; q < 8; ++q) f[q] = 0.f;
        for (int p = 0; p < 49; ++p) {
            const float* src = &enc[(b * 49 + p) * 1280 + c];
            v4f a = *(const v4f*)src, bq = *(const v4f*)(src + 4);
#pragma unroll
            for (int q = 0; q < 4; ++q) { f[q] += a[q]; f[q + 4] += bq[q]; }
        }
#pragma unroll
        for (int q = 0; q < 8; ++q) f[q] *= (1.f / 49.f);
        *(v4i*)&meanb[j] = pack8(f);
    } else if (i < 30461952) {                // bz = b_ih + b_hh
        int j = i - 30457856;
#pragma unroll
        for (int q = 0; q < 8; ++q) f[q] = bih[j + q] + bhh[j + q];
        *(v4f*)&bz[j] = *(v4f*)&f[0]; *(v4f*)&bz[j + 4] = *(v4f*)&f[4];
    }
}

// ---------------------------------------------------------------------------
// gemm64_bn16: C[64,N] = A[64,K](bf16) @ B[N,K](bf16)^T + bias. BN=16/block.
// (used for h0/c0 init only)
// ---------------------------------------------------------------------------
template <int OUT_BF16>
__global__ __launch_bounds__(256) void gemm64_bn16(
    const unsigned short* __restrict__ Ag, int lda,
    const unsigned short* __restrict__ Bg, int K,
    const float* __restrict__ bias, void* __restrict__ Cg, int ldc)
{
    __shared__ unsigned short lA[64 * 264];
    __shared__ unsigned short lB[16 * 264];
    const int tid = threadIdx.x, lane = tid & 63, w = tid >> 6;
    const int nb = blockIdx.x * 16;
    const int rA = tid >> 5, cA = (tid & 31) * 8;
    v4f acc = {0.f, 0.f, 0.f, 0.f};
    v4i ra[8], rb[2];
#pragma unroll
    for (int i = 0; i < 8; ++i)
        ra[i] = *(const v4i*)&Ag[(rA + i * 8) * lda + cA];
#pragma unroll
    for (int i = 0; i < 2; ++i)
        rb[i] = *(const v4i*)&Bg[(nb + rA + i * 8) * K + cA];
    for (int kt = 0; kt < K; kt += 256) {
#pragma unroll
        for (int i = 0; i < 8; ++i) *(v4i*)&lA[(rA + i * 8) * 264 + cA] = ra[i];
#pragma unroll
        for (int i = 0; i < 2; ++i) *(v4i*)&lB[(rA + i * 8) * 264 + cA] = rb[i];
        __syncthreads();
        if (kt + 256 < K) {
#pragma unroll
            for (int i = 0; i < 8; ++i)
                ra[i] = *(const v4i*)&Ag[(rA + i * 8) * lda + kt + 256 + cA];
#pragma unroll
            for (int i = 0; i < 2; ++i)
                rb[i] = *(const v4i*)&Bg[(nb + rA + i * 8) * K + kt + 256 + cA];
        }
#pragma unroll
        for (int ks = 0; ks < 8; ++ks) {
            v8s a = *(const v8s*)&lA[(w * 16 + (lane & 15)) * 264 + ks * 32 + (lane >> 4) * 8];
            v8s b = *(const v8s*)&lB[(lane & 15) * 264 + ks * 32 + (lane >> 4) * 8];
            acc = __builtin_amdgcn_mfma_f32_16x16x32_bf16(a, b, acc, 0, 0, 0);
        }
        __syncthreads();
    }
    const int n = nb + (lane & 15);
    const float bs = bias[n];
#pragma unroll
    for (int r = 0; r < 4; ++r) {
        int m = w * 16 + (lane >> 4) * 4 + r;
        float v = acc[r] + bs;
        if (OUT_BF16) ((unsigned short*)Cg)[m * ldc + n] = f2bf(v);
        else          ((float*)Cg)[m * ldc + n] = v;
    }
}

// ---------------------------------------------------------------------------
// gemm_att1: att1[3136,512](bf16) = enc_b[3136,1280] @ W_eatt[512,1280]^T + b
// ---------------------------------------------------------------------------
__global__ __launch_bounds__(256) void gemm_att1_k(
    const unsigned short* __restrict__ Aenc, const unsigned short* __restrict__ Bw,
    const float* __restrict__ bias, unsigned short* __restrict__ Cout)
{
    __shared__ unsigned short lA[64 * 136];
    __shared__ unsigned short lB[64 * 136];
    const int tid = threadIdx.x, lane = tid & 63, w = tid >> 6;
    const int mb = blockIdx.y * 64, nb = blockIdx.x * 64;
    const int rT = tid >> 4, cT = (tid & 15) * 8;
    v4f acc[4];
#pragma unroll
    for (int f = 0; f < 4; ++f) acc[f] = (v4f){0.f, 0.f, 0.f, 0.f};
    v4i ra[4], rb[4];
#pragma unroll
    for (int i = 0; i < 4; ++i) {
        ra[i] = *(const v4i*)&Aenc[(mb + rT + i * 16) * 1280 + cT];
        rb[i] = *(const v4i*)&Bw[(nb + rT + i * 16) * 1280 + cT];
    }
    for (int kt = 0; kt < 1280; kt += 128) {
#pragma unroll
        for (int i = 0; i < 4; ++i) {
            *(v4i*)&lA[(rT + i * 16) * 136 + cT] = ra[i];
            *(v4i*)&lB[(rT + i * 16) * 136 + cT] = rb[i];
        }
        __syncthreads();
        if (kt + 128 < 1280) {
#pragma unroll
            for (int i = 0; i < 4; ++i) {
                ra[i] = *(const v4i*)&Aenc[(mb + rT + i * 16) * 1280 + kt + 128 + cT];
                rb[i] = *(const v4i*)&Bw[(nb + rT + i * 16) * 1280 + kt + 128 + cT];
            }
        }
#pragma unroll
        for (int ks = 0; ks < 4; ++ks) {
            v8s a = *(const v8s*)&lA[(w * 16 + (lane & 15)) * 136 + ks * 32 + (lane >> 4) * 8];
#pragma unroll
            for (int f = 0; f < 4; ++f) {
                v8s b = *(const v8s*)&lB[(f * 16 + (lane & 15)) * 136 + ks * 32 + (lane >> 4) * 8];
                acc[f] = __builtin_amdgcn_mfma_f32_16x16x32_bf16(a, b, acc[f], 0, 0, 0);
            }
        }
        __syncthreads();
    }
#pragma unroll
    for (int f = 0; f < 4; ++f) {
        int n = nb + f * 16 + (lane & 15);
        float bs = bias[n];
#pragma unroll
        for (int r = 0; r < 4; ++r) {
            int m = mb + w * 16 + (lane >> 4) * 4 + r;
            Cout[m * 512 + n] = f2bf(acc[f][r] + bs);
        }
    }
}

// ---------------------------------------------------------------------------
// loop_k: 24-step decoder loop. grid = 64 blocks x 256 threads, persistent.
// Cross-block data (z, h) moves via agent-coherent atomic loads/stores;
// everything read-only (Wz, Wdatt, att1, enc, Wfatt, bz, embb) uses normal
// cached loads and stays L2-warm for all 24 steps (no invalidates anywhere).
//   phaseA (block b): att2 = h[b]@Wdatt^T + bdatt as in-block GEMV (LDS-local);
//     scores/softmax/ctx; writes z row b = [emb | ctx | h] (coherent).
//   phaseB (block j): gates[64 b x 64 rows] for h-cols [16j,16j+16), all 4
//     gates; K=2816 MFMA GEMM; LSTM epilogue -> h (coherent) + Hall (normal).
//   c-state lives in registers (block j owns its 16 h-cols for all steps).
// ---------------------------------------------------------------------------
struct SmemGemm {
    unsigned short lA[64 * 264];
    unsigned short lB[64 * 264];
    float gbuf[64 * 68];
};
struct SmemAttn {
    float a2[512];
    float wf[512];
    float hf[1024];
    float es[64];
    float alpha[64];
};
union LoopSmem { SmemGemm g; SmemAttn a; };

__global__ __launch_bounds__(256, 1) void loop_k(
    unsigned short* __restrict__ zb,
    const unsigned short* __restrict__ Wdattb, const float* __restrict__ bdatt,
    const unsigned short* __restrict__ att1b, const float* __restrict__ Wfatt,
    const float* __restrict__ bfatt, const unsigned short* __restrict__ encb,
    const unsigned short* __restrict__ embb, const unsigned short* __restrict__ Wzb,
    const float* __restrict__ bz, const float* __restrict__ cst,
    unsigned short* __restrict__ Hallb, unsigned short* __restrict__ hnewb,
    int* __restrict__ barcnt)
{
    __shared__ LoopSmem sm;
    const int tid = threadIdx.x, lane = tid & 63, w = tid >> 6;
    const int bid = blockIdx.x;          // 0..63
    int btarget = 0;

    // registerized c-state: block bid owns h-cols [bid*16, bid*16+16)
    // thread -> (b = tid&63, hc = (tid>>6)*4 + hh), hh = 0..3
    const int cb = tid & 63, hc0 = (tid >> 6) * 4;
    float creg[4];
#pragma unroll
    for (int hh = 0; hh < 4; ++hh)
        creg[hh] = cst[cb * 1024 + bid * 16 + hc0 + hh];

    for (int t = 0; t < 24; ++t) {
        // ============ phaseA: GEMV att2 + attention + z assembly (block b)
        {
            const int b = bid;
            float* a2 = sm.a.a2; float* wf = sm.a.wf; float* hf = sm.a.hf;
            float* es = sm.a.es; float* alpha = sm.a.alpha;
            if (tid < 128) {
                v4i u = cload4(&hnewb[b * 1024 + tid * 8]);     // coherent h read
                cstore4(&zb[b * 2816 + 1792 + tid * 8], u);     // z h-columns
#pragma unroll
                for (int q = 0; q < 4; ++q) {
                    unsigned int x = ((unsigned int*)&u)[q];
                    hf[tid * 8 + 2 * q]     = lo16(x);
                    hf[tid * 8 + 2 * q + 1] = hi16(x);
                }
            }
            wf[tid]       = Wfatt[tid];
            wf[tid + 256] = Wfatt[tid + 256];
            if (tid < 64) {                                     // z emb-columns
                v4i u = *(const v4i*)&embb[(b * 24 + t) * 512 + tid * 8];
                cstore4(&zb[b * 2816 + tid * 8], u);
            }
            __syncthreads();
            // GEMV: thread computes att2 outputs n=tid and n=tid+256.
            {
                const unsigned short* w0 = &Wdattb[(size_t)tid * 1024];
                const unsigned short* w1 = &Wdattb[(size_t)(tid + 256) * 1024];
                float s0 = 0.f, s1 = 0.f, s2 = 0.f, s3 = 0.f;
                for (int k = 0; k < 1024; k += 8) {
                    v4i u0 = *(const v4i*)&w0[k];
                    v4i u1 = *(const v4i*)&w1[k];
#pragma unroll
                    for (int q = 0; q < 4; ++q) {
                        unsigned int x0 = ((unsigned int*)&u0)[q];
                        unsigned int x1 = ((unsigned int*)&u1)[q];
                        float ha = hf[k + 2 * q], hb2 = hf[k + 2 * q + 1];
                        s0 += lo16(x0) * ha; s1 += hi16(x0) * hb2;
                        s2 += lo16(x1) * ha; s3 += hi16(x1) * hb2;
                    }
                }
                a2[tid]       = s0 + s1 + bdatt[tid];
                a2[tid + 256] = s2 + s3 + bdatt[tid + 256];
            }
            __syncthreads();
            // scores: one att1 row per wave-iteration
            for (int p = w; p < 49; p += 4) {
                v4i u = *(const v4i*)&att1b[(b * 49 + p) * 512 + lane * 8];
                v4f c0 = *(const v4f*)&a2[lane * 8], c1 = *(const v4f*)&a2[lane * 8 + 4];
                v4f w0 = *(const v4f*)&wf[lane * 8], w1 = *(const v4f*)&wf[lane * 8 + 4];
                float s = 0.f;
#pragma unroll
                for (int q = 0; q < 4; ++q) {
                    unsigned int x = ((unsigned int*)&u)[q];
                    float vlo = lo16(x), vhi = hi16(x);
                    float clo = (q < 2) ? c0[q * 2] : c1[q * 2 - 4];
                    float chi = (q < 2) ? c0[q * 2 + 1] : c1[q * 2 - 3];
                    float wlo = (q < 2) ? w0[q * 2] : w1[q * 2 - 4];
                    float whi = (q < 2) ? w0[q * 2 + 1] : w1[q * 2 - 3];
                    s += fmaxf(vlo + clo, 0.f) * wlo;
                    s += fmaxf(vhi + chi, 0.f) * whi;
                }
#pragma unroll
                for (int off = 32; off > 0; off >>= 1) s += __shfl_xor(s, off);
                if (lane == 0) es[p] = s + bfatt[0];
            }
            __syncthreads();
            if (w == 0) {
                float v = (lane < 49) ? es[lane] : -1e30f;
                float m = v;
#pragma unroll
                for (int off = 32; off > 0; off >>= 1) m = fmaxf(m, __shfl_xor(m, off));
                float e = (lane < 49) ? __expf(v - m) : 0.f;
                float s = e;
#pragma unroll
                for (int off = 32; off > 0; off >>= 1) s += __shfl_xor(s, off);
                if (lane < 49) alpha[lane] = e / s;
            }
            __syncthreads();
            if (tid < 160) {                                    // z ctx-columns
                const int jb = tid * 8;
                float acc[8];
#pragma unroll
                for (int q = 0; q < 8; ++q) acc[q] = 0.f;
                for (int p = 0; p < 49; ++p) {
                    v4i u = *(const v4i*)&encb[(b * 49 + p) * 1280 + jb];
                    float al = alpha[p];
#pragma unroll
                    for (int q = 0; q < 4; ++q) {
                        unsigned int x = ((unsigned int*)&u)[q];
                        acc[2 * q]     += al * lo16(x);
                        acc[2 * q + 1] += al * hi16(x);
                    }
                }
                cstore4(&zb[b * 2816 + 512 + jb], pack8(acc));
            }
        }
        btarget += 64; gbar(barcnt, btarget);

        // ============ phaseB: gates GEMM (64 b x 64 rows) + LSTM epilogue
        {
            const int j = bid;
            const int rT = tid >> 5, cT = (tid & 31) * 8;   // rT 0..7, cT 0..248
            // local B row lr = rT + i*8 -> Wz row (lr>>4)*1024 + j*16 + (lr&15)
            v4f acc[4];
#pragma unroll
            for (int f = 0; f < 4; ++f) acc[f] = (v4f){0.f, 0.f, 0.f, 0.f};
            v4i ra[8], rb[8];
#pragma unroll
            for (int i = 0; i < 8; ++i) {
                ra[i] = cload4(&zb[(rT + i * 8) * 2816 + cT]);  // coherent z read
                int lr = rT + i * 8;
                rb[i] = *(const v4i*)&Wzb[((lr >> 4) * 1024 + j * 16 + (lr & 15)) * 2816 + cT];
            }
            for (int kt = 0; kt < 2816; kt += 256) {
#pragma unroll
                for (int i = 0; i < 8; ++i) {
                    *(v4i*)&sm.g.lA[(rT + i * 8) * 264 + cT] = ra[i];
                    *(v4i*)&sm.g.lB[(rT + i * 8) * 264 + cT] = rb[i];
                }
                __syncthreads();
                if (kt + 256 < 2816) {
#pragma unroll
                    for (int i = 0; i < 8; ++i) {
                        ra[i] = cload4(&zb[(rT + i * 8) * 2816 + kt + 256 + cT]);
                        int lr = rT + i * 8;
                        rb[i] = *(const v4i*)&Wzb[((lr >> 4) * 1024 + j * 16 + (lr & 15)) * 2816 + kt + 256 + cT];
                    }
                }
#pragma unroll
                for (int ks = 0; ks < 8; ++ks) {
                    v8s a = *(const v8s*)&sm.g.lA[(w * 16 + (lane & 15)) * 264 + ks * 32 + (lane >> 4) * 8];
#pragma unroll
                    for (int f = 0; f < 4; ++f) {
                        v8s b = *(const v8s*)&sm.g.lB[(f * 16 + (lane & 15)) * 264 + ks * 32 + (lane >> 4) * 8];
                        acc[f] = __builtin_amdgcn_mfma_f32_16x16x32_bf16(a, b, acc[f], 0, 0, 0);
                    }
                }
                __syncthreads();
            }
#pragma unroll
            for (int f = 0; f < 4; ++f)
#pragma unroll
                for (int r = 0; r < 4; ++r) {
                    int m = w * 16 + (lane >> 4) * 4 + r;   // b index
                    int n = f * 16 + (lane & 15);           // local row: gate=n>>4, hc=n&15
                    sm.g.gbuf[m * 68 + n] = acc[f][r];
                }
            __syncthreads();
            // LSTM epilogue: thread -> b = tid&63, hcols hc0..hc0+3
            unsigned short h16[4];
#pragma unroll
            for (int hh = 0; hh < 4; ++hh) {
                int hc = hc0 + hh, hidx = j * 16 + hc;
                float gi = sm.g.gbuf[cb * 68 +      hc] + bz[hidx];
                float gf = sm.g.gbuf[cb * 68 + 16 + hc] + bz[1024 + hidx];
                float gg = sm.g.gbuf[cb * 68 + 32 + hc] + bz[2048 + hidx];
                float go = sm.g.gbuf[cb * 68 + 48 + hc] + bz[3072 + hidx];
                float cn = sigm(gf) * creg[hh] + sigm(gi) * tanhf(gg);
                float hn = sigm(go) * tanhf(cn);
                creg[hh] = cn;
                h16[hh] = f2bf(hn);
            }
            unsigned int lo = (unsigned int)h16[0] | ((unsigned int)h16[1] << 16);
            unsigned int hi = (unsigned int)h16[2] | ((unsigned int)h16[3] << 16);
            unsigned int base = (unsigned int)(cb * 1024 + j * 16 + hc0);
            cstoreu((unsigned int*)&hnewb[base], lo);           // coherent h write
            cstoreu((unsigned int*)&hnewb[base] + 1, hi);
            *(unsigned int*)&Hallb[(size_t)t * 65536 + base] = lo;   // normal store
            *((unsigned int*)&Hallb[(size_t)t * 65536 + base] + 1) = hi;
        }
        if (t < 23) { btarget += 64; gbar(barcnt, btarget); }
        // final step: kernel completion flushes Hallb before preds_k
    }
}

// ---------------------------------------------------------------------------
// preds: out = Hall[1536,1024] @ W_out[10000,1024]^T + b_out
// Tile 128x128, BK=64, reg-dbuf. grid = 960 with XCD-aware mapping so all 12
// m-blocks of one Wout n-strip land on the same XCD (strip fetched once).
// ---------------------------------------------------------------------------
__global__ __launch_bounds__(256) void preds_k(
    const unsigned short* __restrict__ Hall, const unsigned short* __restrict__ Wout,
    const float* __restrict__ bout, float* __restrict__ out)
{
    const int bidl = blockIdx.x;
    const int xcd = bidl & 7, loc = bidl >> 3;
    const int nbi = xcd * 10 + loc / 12;
    const int mbi = loc - (loc / 12) * 12;
    if (nbi >= 79) return;
    __shared__ unsigned short lA[128 * 72];
    __shared__ unsigned short lB[128 * 72];
    const int tid = threadIdx.x, lane = tid & 63, w = tid >> 6;
    const int mb = mbi * 128, nb = nbi * 128;
    const int rT = tid >> 3, cT = (tid & 7) * 8;
    v4f acc[2][8];
#pragma unroll
    for (int i = 0; i < 2; ++i)
#pragma unroll
        for (int f = 0; f < 8; ++f) acc[i][f] = (v4f){0.f, 0.f, 0.f, 0.f};
    v4i ra[4], rb[4];
#pragma unroll
    for (int i = 0; i < 4; ++i) {
        ra[i] = *(const v4i*)&Hall[(mb + rT + i * 32) * 1024 + cT];
        int n2 = nb + rT + i * 32; if (n2 > 9999) n2 = 9999;
        rb[i] = *(const v4i*)&Wout[n2 * 1024 + cT];
    }
    for (int kt = 0; kt < 1024; kt += 64) {
#pragma unroll
        for (int i = 0; i < 4; ++i) {
            *(v4i*)&lA[(rT + i * 32) * 72 + cT] = ra[i];
            *(v4i*)&lB[(rT + i * 32) * 72 + cT] = rb[i];
        }
        __syncthreads();
        if (kt + 64 < 1024) {
#pragma unroll
            for (int i = 0; i < 4; ++i) {
                ra[i] = *(const v4i*)&Hall[(mb + rT + i * 32) * 1024 + kt + 64 + cT];
                int n2 = nb + rT + i * 32; if (n2 > 9999) n2 = 9999;
                rb[i] = *(const v4i*)&Wout[n2 * 1024 + kt + 64 + cT];
            }
        }
#pragma unroll
        for (int ks = 0; ks < 2; ++ks) {
            int ko = ks * 32 + (lane >> 4) * 8;
            v8s a0 = *(const v8s*)&lA[(w * 32 + (lane & 15)) * 72 + ko];
            v8s a1 = *(const v8s*)&lA[(w * 32 + 16 + (lane & 15)) * 72 + ko];
#pragma unroll
            for (int f = 0; f < 8; ++f) {
                v8s b = *(const v8s*)&lB[(f * 16 + (lane & 15)) * 72 + ko];
                acc[0][f] = __builtin_amdgcn_mfma_f32_16x16x32_bf16(a0, b, acc[0][f], 0, 0, 0);
                acc[1][f] = __builtin_amdgcn_mfma_f32_16x16x32_bf16(a1, b, acc[1][f], 0, 0, 0);
            }
        }
        __syncthreads();
    }
#pragma unroll
    for (int f = 0; f < 8; ++f) {
        int n = nb + f * 16 + (lane & 15);
        if (n < 10000) {
            float bs = bout[n];
#pragma unroll
            for (int i = 0; i < 2; ++i)
#pragma unroll
                for (int r = 0; r < 4; ++r) {
                    int m = mb + w * 32 + i * 16 + (lane >> 4) * 4 + r;
                    int tt = m >> 6, bb = m & 63;
                    out[(bb * 24 + tt) * 10000 + n] = acc[i][f][r] + bs;
                }
        }
    }
}

// ---------------------------------------------------------------------------
extern "C" void kernel_launch(void* const* d_in, const int* in_sizes, int n_in,
                              void* d_out, int out_size, void* d_ws, size_t ws_size,
                              hipStream_t stream)
{
    const float* enc   = (const float*)d_in[0];
    const int*   caps  = (const int*)d_in[1];
    const float* embed = (const float*)d_in[2];
    const float* Weatt = (const float*)d_in[3];
    const float* beatt = (const float*)d_in[4];
    const float* Wdatt = (const float*)d_in[5];
    const float* bdatt = (const float*)d_in[6];
    const float* Wfatt = (const float*)d_in[7];
    const float* bfatt = (const float*)d_in[8];
    const float* Wih   = (const float*)d_in[9];
    const float* bih   = (const float*)d_in[10];
    const float* Whh   = (const float*)d_in[11];
    const float* bhh   = (const float*)d_in[12];
    const float* Wh0   = (const float*)d_in[13];
    const float* bh0   = (const float*)d_in[14];
    const float* Wc0   = (const float*)d_in[15];
    const float* bc0   = (const float*)d_in[16];
    const float* WoutF = (const float*)d_in[17];
    const float* bout  = (const float*)d_in[18];
    float* out = (float*)d_out;

    char* ws = (char*)d_ws;
    size_t off = 0;
    auto carve = [&](size_t bytes) -> void* {
        void* p = ws + off; off += (bytes + 255) & ~(size_t)255; return p;
    };
    unsigned short* Wzb    = (unsigned short*)carve(11534336ull * 2);
    unsigned short* Woutb  = (unsigned short*)carve(10240000ull * 2);
    unsigned short* Weattb = (unsigned short*)carve(655360ull * 2);
    unsigned short* Wdattb = (unsigned short*)carve(524288ull * 2);
    unsigned short* Wh0b   = (unsigned short*)carve(1310720ull * 2);
    unsigned short* Wc0b   = (unsigned short*)carve(1310720ull * 2);
    unsigned short* encb   = (unsigned short*)carve(4014080ull * 2);
    unsigned short* embb   = (unsigned short*)carve(786432ull * 2);
    unsigned short* meanb  = (unsigned short*)carve(81920ull * 2);
    unsigned short* att1b  = (unsigned short*)carve(1605632ull * 2);
    unsigned short* Hallb  = (unsigned short*)carve(1572864ull * 2);
    unsigned short* zb     = (unsigned short*)carve(180224ull * 2);
    unsigned short* hnewb  = (unsigned short*)carve(65536ull * 2);
    float* bz   = (float*)carve(4096ull * 4);
    float* cst  = (float*)carve(65536ull * 4);
    int*   barcnt = (int*)carve(256);

    // barrier counter must be 0 at loop_k entry every iteration
    hipMemsetAsync(barcnt, 0, 256, stream);

    uber_init<<<14874, 256, 0, stream>>>(Wih, Whh, bih, bhh, WoutF, Weatt, Wdatt,
        Wh0, Wc0, enc, caps, embed, Wzb, Woutb, Weattb, Wdattb, Wh0b, Wc0b,
        encb, embb, meanb, bz);

    // h0 -> hnewb (bf16, ldc=1024); c0 -> cst (f32)
    gemm64_bn16<1><<<64, 256, 0, stream>>>(meanb, 1280, Wh0b, 1280, bh0, hnewb, 1024);
    gemm64_bn16<0><<<64, 256, 0, stream>>>(meanb, 1280, Wc0b, 1280, bc0, cst, 1024);

    gemm_att1_k<<<dim3(8, 49), 256, 0, stream>>>(encb, Weattb, beatt, att1b);

    // whole 24-step decoder loop, one persistent kernel, fence-free barriers
    loop_k<<<64, 256, 0, stream>>>(zb, Wdattb, bdatt, att1b, Wfatt,
        bfatt, encb, embb, Wzb, bz, cst, Hallb, hnewb, barcnt);

    preds_k<<<960, 256, 0, stream>>>(Hallb, Woutb, bout, out);
}

// Round 7
// 2152.454 us; speedup vs baseline: 1.3151x; 1.3151x over previous
//
#include <hip/hip_runtime.h>
#include <hip/hip_bf16.h>

typedef float  v4f __attribute__((ext_vector_type(4)));
typedef short  v8s __attribute__((ext_vector_type(8)));
typedef int    v4i __attribute__((ext_vector_type(4)));

#define DEV static __device__ __forceinline__

DEV float bf2f(unsigned short u) {
    union { unsigned int i; float f; } x; x.i = ((unsigned int)u) << 16; return x.f;
}
DEV unsigned short f2bf(float f) {
    union { float f; unsigned int i; } x; x.f = f;
    unsigned int r = x.i + 0x7fff + ((x.i >> 16) & 1);
    return (unsigned short)(r >> 16);
}
DEV float sigm(float x) { return 1.f / (1.f + __expf(-x)); }

DEV v4i pack8(const float* f) {
    v4i o;
#pragma unroll
    for (int q = 0; q < 4; ++q)
        ((unsigned int*)&o)[q] = (unsigned int)f2bf(f[2 * q]) |
                                 ((unsigned int)f2bf(f[2 * q + 1]) << 16);
    return o;
}
DEV float lo16(unsigned int x) { union { unsigned int i; float f; } u; u.i = x << 16; return u.f; }
DEV float hi16(unsigned int x) { union { unsigned int i; float f; } u; u.i = x & 0xffff0000u; return u.f; }

// Coherent (agent-scope, relaxed) stores: write through to the MALL coherence
// point (validated round 5). Producers of z/h use these; consumers use NORMAL
// cached loads on ROTATING per-step buffers -- every slot is first-touch
// within the launch (L2 invalidated at kernel begin, no address re-read
// across steps), so a clean miss fetches fresh MALL data. No fences, no
// invalidates, no coherent loads anywhere on the hot path.
DEV void cstoreu(unsigned int* p, unsigned int v) {
    __hip_atomic_store(p, v, __ATOMIC_RELAXED, __HIP_MEMORY_SCOPE_AGENT);
}
DEV void cstore4(unsigned short* p, v4i v) {
    unsigned int* q = (unsigned int*)p;
    cstoreu(q,     ((unsigned int*)&v)[0]);
    cstoreu(q + 1, ((unsigned int*)&v)[1]);
    cstoreu(q + 2, ((unsigned int*)&v)[2]);
    cstoreu(q + 3, ((unsigned int*)&v)[3]);
}

// Grid barrier: relaxed RMW arrive + relaxed RMW spin (RMWs always serviced
// at the coherence point -> observe remote arrivals; no wbl2/inv). The
// __syncthreads() before arrival drains vmcnt -> coherent stores acked at
// MALL before the arrive RMW. Validated round 5.
DEV void gbar(int* cnt, int target) {
    __syncthreads();
    if (threadIdx.x == 0) {
        __hip_atomic_fetch_add(cnt, 1, __ATOMIC_RELAXED, __HIP_MEMORY_SCOPE_AGENT);
        while (__hip_atomic_fetch_add(cnt, 0, __ATOMIC_RELAXED, __HIP_MEMORY_SCOPE_AGENT) < target)
            __builtin_amdgcn_s_sleep(32);
        asm volatile("" ::: "memory");
    }
    __syncthreads();
}

// ---------------------------------------------------------------------------
// uber_init: 8 elements per thread. Only converts what the loop needs as
// bf16 (Wz, W_eatt, W_datt, enc, emb gather, mean, bz). W_out / W_h0 / W_c0
// are consumed as f32 directly by their GEMMs (workspace -25.7 MB).
// ---------------------------------------------------------------------------
__global__ __launch_bounds__(256) void uber_init(
    const float* __restrict__ Wih, const float* __restrict__ Whh,
    const float* __restrict__ bih, const float* __restrict__ bhh,
    const float* __restrict__ WeattF, const float* __restrict__ WdattF,
    const float* __restrict__ enc, const int* __restrict__ caps,
    const float* __restrict__ embed,
    unsigned short* __restrict__ Wz, unsigned short* __restrict__ Weattb,
    unsigned short* __restrict__ Wdattb, unsigned short* __restrict__ encb,
    unsigned short* __restrict__ embb, unsigned short* __restrict__ meanb,
    float* __restrict__ bz)
{
    const int i = (blockIdx.x * 256 + threadIdx.x) * 8;
    float f[8];
    if (i < 11534336) {                       // Wz = [W_ih | W_hh] rows of 2816
        int n = i / 2816, k = i - n * 2816;
        const float* src = (k < 1792) ? &Wih[n * 1792 + k] : &Whh[n * 1024 + (k - 1792)];
        *(v4f*)&f[0] = *(const v4f*)src; *(v4f*)&f[4] = *(const v4f*)(src + 4);
        *(v4i*)&Wz[i] = pack8(f);
    } else if (i < 12189696) {                // W_eatt
        int j = i - 11534336;
        *(v4f*)&f[0] = *(const v4f*)&WeattF[j]; *(v4f*)&f[4] = *(const v4f*)&WeattF[j + 4];
        *(v4i*)&Weattb[j] = pack8(f);
    } else if (i < 12713984) {                // W_datt
        int j = i - 12189696;
        *(v4f*)&f[0] = *(const v4f*)&WdattF[j]; *(v4f*)&f[4] = *(const v4f*)&WdattF[j + 4];
        *(v4i*)&Wdattb[j] = pack8(f);
    } else if (i < 16728064) {                // encoder_out
        int j = i - 12713984;
        *(v4f*)&f[0] = *(const v4f*)&enc[j]; *(v4f*)&f[4] = *(const v4f*)&enc[j + 4];
        *(v4i*)&encb[j] = pack8(f);
    } else if (i < 17514496) {                // emb gather (t < 24 only)
        int j = i - 16728064;
        int b = j / 12288, r = j - b * 12288, t = r / 512, e = r - t * 512;
        const float* src = &embed[caps[b * 25 + t] * 512 + e];
        *(v4f*)&f[0] = *(const v4f*)src; *(v4f*)&f[4] = *(const v4f*)(src + 4);
        *(v4i*)&embb[j] = pack8(f);
    } else if (i < 17596416) {                // mean over P=49
        int j = i - 17514496;
        int b = j / 1280, c = j - b * 1280;
#pragma unroll
        for (int q = 0; q < 8; ++q) f[q] = 0.f;
        for (int p = 0; p < 49; ++p) {
            const float* src = &enc[(b * 49 + p) * 1280 + c];
            v4f a = *(const v4f*)src, bq = *(const v4f*)(src + 4);
#pragma unroll
            for (int q = 0; q < 4; ++q) { f[q] += a[q]; f[q + 4] += bq[q]; }
        }
#pragma unroll
        for (int q = 0; q < 8; ++q) f[q] *= (1.f / 49.f);
        *(v4i*)&meanb[j] = pack8(f);
    } else if (i < 17600512) {                // bz = b_ih + b_hh
        int j = i - 17596416;
#pragma unroll
        for (int q = 0; q < 8; ++q) f[q] = bih[j + q] + bhh[j + q];
        *(v4f*)&bz[j] = *(v4f*)&f[0]; *(v4f*)&bz[j + 4] = *(v4f*)&f[4];
    }
}

// ---------------------------------------------------------------------------
// gemm64_f32B: C[64,N] = A[64,K](bf16) @ B[N,K](f32, converted inline)^T + b.
// BN=16 per block. Used for h0/c0 init only (B = W_h0 / W_c0 as raw f32).
// ---------------------------------------------------------------------------
template <int OUT_BF16>
__global__ __launch_bounds__(256) void gemm64_f32B(
    const unsigned short* __restrict__ Ag, int lda,
    const float* __restrict__ BgF, int K,
    const float* __restrict__ bias, void* __restrict__ Cg, int ldc)
{
    __shared__ unsigned short lA[64 * 264];
    __shared__ unsigned short lB[16 * 264];
    const int tid = threadIdx.x, lane = tid & 63, w = tid >> 6;
    const int nb = blockIdx.x * 16;
    const int rA = tid >> 5, cA = (tid & 31) * 8;
    v4f acc = {0.f, 0.f, 0.f, 0.f};
    v4i ra[8];
    v4f rbf[2][2];
#pragma unroll
    for (int i = 0; i < 8; ++i)
        ra[i] = *(const v4i*)&Ag[(rA + i * 8) * lda + cA];
#pragma unroll
    for (int i = 0; i < 2; ++i) {
        const float* src = &BgF[(size_t)(nb + rA + i * 8) * K + cA];
        rbf[i][0] = *(const v4f*)src; rbf[i][1] = *(const v4f*)(src + 4);
    }
    for (int kt = 0; kt < K; kt += 256) {
#pragma unroll
        for (int i = 0; i < 8; ++i) *(v4i*)&lA[(rA + i * 8) * 264 + cA] = ra[i];
#pragma unroll
        for (int i = 0; i < 2; ++i)
            *(v4i*)&lB[(rA + i * 8) * 264 + cA] = pack8((const float*)&rbf[i][0]);
        __syncthreads();
        if (kt + 256 < K) {
#pragma unroll
            for (int i = 0; i < 8; ++i)
                ra[i] = *(const v4i*)&Ag[(rA + i * 8) * lda + kt + 256 + cA];
#pragma unroll
            for (int i = 0; i < 2; ++i) {
                const float* src = &BgF[(size_t)(nb + rA + i * 8) * K + kt + 256 + cA];
                rbf[i][0] = *(const v4f*)src; rbf[i][1] = *(const v4f*)(src + 4);
            }
        }
#pragma unroll
        for (int ks = 0; ks < 8; ++ks) {
            v8s a = *(const v8s*)&lA[(w * 16 + (lane & 15)) * 264 + ks * 32 + (lane >> 4) * 8];
            v8s b = *(const v8s*)&lB[(lane & 15) * 264 + ks * 32 + (lane >> 4) * 8];
            acc = __builtin_amdgcn_mfma_f32_16x16x32_bf16(a, b, acc, 0, 0, 0);
        }
        __syncthreads();
    }
    const int n = nb + (lane & 15);
    const float bs = bias[n];
#pragma unroll
    for (int r = 0; r < 4; ++r) {
        int m = w * 16 + (lane >> 4) * 4 + r;
        float v = acc[r] + bs;
        if (OUT_BF16) ((unsigned short*)Cg)[m * ldc + n] = f2bf(v);
        else          ((float*)Cg)[m * ldc + n] = v;
    }
}

// ---------------------------------------------------------------------------
// gemm_att1: att1[3136,512](bf16) = enc_b[3136,1280] @ W_eatt[512,1280]^T + b
// ---------------------------------------------------------------------------
__global__ __launch_bounds__(256) void gemm_att1_k(
    const unsigned short* __restrict__ Aenc, const unsigned short* __restrict__ Bw,
    const float* __restrict__ bias, unsigned short* __restrict__ Cout)
{
    __shared__ unsigned short lA[64 * 136];
    __shared__ unsigned short lB[64 * 136];
    const int tid = threadIdx.x, lane = tid & 63, w = tid >> 6;
    const int mb = blockIdx.y * 64, nb = blockIdx.x * 64;
    const int rT = tid >> 4, cT = (tid & 15) * 8;
    v4f acc[4];
#pragma unroll
    for (int f = 0; f < 4; ++f) acc[f] = (v4f){0.f, 0.f, 0.f, 0.f};
    v4i ra[4], rb[4];
#pragma unroll
    for (int i = 0; i < 4; ++i) {
        ra[i] = *(const v4i*)&Aenc[(mb + rT + i * 16) * 1280 + cT];
        rb[i] = *(const v4i*)&Bw[(nb + rT + i * 16) * 1280 + cT];
    }
    for (int kt = 0; kt < 1280; kt += 128) {
#pragma unroll
        for (int i = 0; i < 4; ++i) {
            *(v4i*)&lA[(rT + i * 16) * 136 + cT] = ra[i];
            *(v4i*)&lB[(rT + i * 16) * 136 + cT] = rb[i];
        }
        __syncthreads();
        if (kt + 128 < 1280) {
#pragma unroll
            for (int i = 0; i < 4; ++i) {
                ra[i] = *(const v4i*)&Aenc[(mb + rT + i * 16) * 1280 + kt + 128 + cT];
                rb[i] = *(const v4i*)&Bw[(nb + rT + i * 16) * 1280 + kt + 128 + cT];
            }
        }
#pragma unroll
        for (int ks = 0; ks < 4; ++ks) {
            v8s a = *(const v8s*)&lA[(w * 16 + (lane & 15)) * 136 + ks * 32 + (lane >> 4) * 8];
#pragma unroll
            for (int f = 0; f < 4; ++f) {
                v8s b = *(const v8s*)&lB[(f * 16 + (lane & 15)) * 136 + ks * 32 + (lane >> 4) * 8];
                acc[f] = __builtin_amdgcn_mfma_f32_16x16x32_bf16(a, b, acc[f], 0, 0, 0);
            }
        }
        __syncthreads();
    }
#pragma unroll
    for (int f = 0; f < 4; ++f) {
        int n = nb + f * 16 + (lane & 15);
        float bs = bias[n];
#pragma unroll
        for (int r = 0; r < 4; ++r) {
            int m = mb + w * 16 + (lane >> 4) * 4 + r;
            Cout[m * 512 + n] = f2bf(acc[f][r] + bs);
        }
    }
}

// ---------------------------------------------------------------------------
// loop_k: 24-step decoder loop. grid = 256 blocks x 256 threads, 47.9 KB LDS
// -> 3 blocks/CU capacity (768 >= 256: co-residency guaranteed with margin,
// round-6 lesson). Rotating z/h buffers: producers use coherent MALL stores,
// consumers use normal cached loads (first-touch per slot). Read-only data
// (Wz, Wdatt, att1, enc, emb, bz) uses normal cached loads, never invalidated.
//   phaseA (blocks 0..63, block b): att2 GEMV in LDS + scores/softmax/ctx;
//     writes z[t] row b = [emb | ctx | h[t] row b].
//   phaseB (all 256, block j): gates[64 x 16] for h-cols [4j,4j+4) x 4 gates,
//     K=2816 MFMA GEMM; LSTM epilogue -> h[t+1] (coherent) + Hall (normal).
//   c-state in registers (block j owns its 4 h-cols all steps).
// ---------------------------------------------------------------------------
struct SmemGemm {
    unsigned short lA[64 * 264];
    unsigned short lB[16 * 264];
    float gbuf[64 * 20];
};
struct SmemAttn {
    float a2[512];
    float wf[512];
    float hf[1024];
    float es[64];
    float alpha[64];
};
struct LoopSmem {
    union { SmemGemm g; SmemAttn a; } u;     // 47360 B
    unsigned short sm_h[256];                //   512 B
};                                           // 47872 B -> 3 blocks/CU

__global__ __launch_bounds__(256, 1) void loop_k(
    unsigned short* __restrict__ zseq,        // 24 x [64][2816]
    const unsigned short* __restrict__ Wdattb, const float* __restrict__ bdatt,
    const unsigned short* __restrict__ att1b, const float* __restrict__ Wfatt,
    const float* __restrict__ bfatt, const unsigned short* __restrict__ encb,
    const unsigned short* __restrict__ embb, const unsigned short* __restrict__ Wzb,
    const float* __restrict__ bz, const float* __restrict__ cst,
    unsigned short* __restrict__ Hallb,
    unsigned short* __restrict__ hseq,        // 25 x [64][1024]; slot 0 = h0
    int* __restrict__ barcnt)
{
    __shared__ LoopSmem sm;
    const int tid = threadIdx.x, lane = tid & 63, w = tid >> 6;
    const int bid = blockIdx.x;          // 0..255
    int btarget = 0;

    // registerized c-state: block bid owns h-cols [bid*4, bid*4+4)
    const int cb = tid >> 2, hc = tid & 3;
    float creg = cst[cb * 1024 + bid * 4 + hc];

    for (int t = 0; t < 24; ++t) {
        unsigned short* zt = zseq + t * 180224;
        const unsigned short* ht = hseq + t * 65536;

        // ============ phaseA: GEMV att2 + attention + z assembly (blocks 0..63)
        if (bid < 64) {
            const int b = bid;
            float* a2 = sm.u.a.a2; float* wf = sm.u.a.wf; float* hf = sm.u.a.hf;
            float* es = sm.u.a.es; float* alpha = sm.u.a.alpha;
            if (tid < 128) {
                v4i u = *(const v4i*)&ht[b * 1024 + tid * 8];   // normal (first touch)
                cstore4(&zt[b * 2816 + 1792 + tid * 8], u);     // z h-columns
#pragma unroll
                for (int q = 0; q < 4; ++q) {
                    unsigned int x = ((unsigned int*)&u)[q];
                    hf[tid * 8 + 2 * q]     = lo16(x);
                    hf[tid * 8 + 2 * q + 1] = hi16(x);
                }
            }
            wf[tid]       = Wfatt[tid];
            wf[tid + 256] = Wfatt[tid + 256];
            if (tid < 64) {                                     // z emb-columns
                v4i u = *(const v4i*)&embb[(b * 24 + t) * 512 + tid * 8];
                cstore4(&zt[b * 2816 + tid * 8], u);
            }
            __syncthreads();
            // GEMV: thread computes att2 outputs n=tid and n=tid+256.
            {
                const unsigned short* w0 = &Wdattb[(size_t)tid * 1024];
                const unsigned short* w1 = &Wdattb[(size_t)(tid + 256) * 1024];
                float s0 = 0.f, s1 = 0.f, s2 = 0.f, s3 = 0.f;
                for (int k = 0; k < 1024; k += 8) {
                    v4i u0 = *(const v4i*)&w0[k];
                    v4i u1 = *(const v4i*)&w1[k];
#pragma unroll
                    for (int q = 0; q < 4; ++q) {
                        unsigned int x0 = ((unsigned int*)&u0)[q];
                        unsigned int x1 = ((unsigned int*)&u1)[q];
                        float ha = hf[k + 2 * q], hb2 = hf[k + 2 * q + 1];
                        s0 += lo16(x0) * ha; s1 += hi16(x0) * hb2;
                        s2 += lo16(x1) * ha; s3 += hi16(x1) * hb2;
                    }
                }
                a2[tid]       = s0 + s1 + bdatt[tid];
                a2[tid + 256] = s2 + s3 + bdatt[tid + 256];
            }
            __syncthreads();
            // scores
            for (int p = w; p < 49; p += 4) {
                v4i u = *(const v4i*)&att1b[(b * 49 + p) * 512 + lane * 8];
                v4f c0 = *(const v4f*)&a2[lane * 8], c1 = *(const v4f*)&a2[lane * 8 + 4];
                v4f w0 = *(const v4f*)&wf[lane * 8], w1 = *(const v4f*)&wf[lane * 8 + 4];
                float s = 0.f;
#pragma unroll
                for (int q = 0; q < 4; ++q) {
                    unsigned int x = ((unsigned int*)&u)[q];
                    float vlo = lo16(x), vhi = hi16(x);
                    float clo = (q < 2) ? c0[q * 2] : c1[q * 2 - 4];
                    float chi = (q < 2) ? c0[q * 2 + 1] : c1[q * 2 - 3];
                    float wlo = (q < 2) ? w0[q * 2] : w1[q * 2 - 4];
                    float whi = (q < 2) ? w0[q * 2 + 1] : w1[q * 2 - 3];
                    s += fmaxf(vlo + clo, 0.f) * wlo;
                    s += fmaxf(vhi + chi, 0.f) * whi;
                }
#pragma unroll
                for (int off = 32; off > 0; off >>= 1) s += __shfl_xor(s, off);
                if (lane == 0) es[p] = s + bfatt[0];
            }
            __syncthreads();
            if (w == 0) {
                float v = (lane < 49) ? es[lane] : -1e30f;
                float m = v;
#pragma unroll
                for (int off = 32; off > 0; off >>= 1) m = fmaxf(m, __shfl_xor(m, off));
                float e = (lane < 49) ? __expf(v - m) : 0.f;
                float s = e;
#pragma unroll
                for (int off = 32; off > 0; off >>= 1) s += __shfl_xor(s, off);
                if (lane < 49) alpha[lane] = e / s;
            }
            __syncthreads();
            if (tid < 160) {                                    // z ctx-columns
                const int jb = tid * 8;
                float acc[8];
#pragma unroll
                for (int q = 0; q < 8; ++q) acc[q] = 0.f;
                for (int p = 0; p < 49; ++p) {
                    v4i u = *(const v4i*)&encb[(b * 49 + p) * 1280 + jb];
                    float al = alpha[p];
#pragma unroll
                    for (int q = 0; q < 4; ++q) {
                        unsigned int x = ((unsigned int*)&u)[q];
                        acc[2 * q]     += al * lo16(x);
                        acc[2 * q + 1] += al * hi16(x);
                    }
                }
                cstore4(&zt[b * 2816 + 512 + jb], pack8(acc));
            }
        }
        btarget += 256; gbar(barcnt, btarget);

        // ============ phaseB: gates GEMM + LSTM epilogue (all 256 blocks)
        {
            const int hb = bid * 4;
            const int rT = tid >> 5, cT = (tid & 31) * 8;
            const int gate = rT & 3, hco = rT >> 2;
            const int growB  = (gate * 1024 + hb + hco) * 2816;
            const int growB2 = (((rT + 8) & 3) * 1024 + hb + ((rT + 8) >> 2)) * 2816;
            v4f acc = {0.f, 0.f, 0.f, 0.f};
            v4i ra[8], rb[2];
#pragma unroll
            for (int i = 0; i < 8; ++i)
                ra[i] = *(const v4i*)&zt[(rT + i * 8) * 2816 + cT];   // normal load
            rb[0] = *(const v4i*)&Wzb[growB + cT];
            rb[1] = *(const v4i*)&Wzb[growB2 + cT];
            for (int kt = 0; kt < 2816; kt += 256) {
#pragma unroll
                for (int i = 0; i < 8; ++i) *(v4i*)&sm.u.g.lA[(rT + i * 8) * 264 + cT] = ra[i];
                *(v4i*)&sm.u.g.lB[rT * 264 + cT] = rb[0];
                *(v4i*)&sm.u.g.lB[(rT + 8) * 264 + cT] = rb[1];
                __syncthreads();
                if (kt + 256 < 2816) {
#pragma unroll
                    for (int i = 0; i < 8; ++i)
                        ra[i] = *(const v4i*)&zt[(rT + i * 8) * 2816 + kt + 256 + cT];
                    rb[0] = *(const v4i*)&Wzb[growB + kt + 256 + cT];
                    rb[1] = *(const v4i*)&Wzb[growB2 + kt + 256 + cT];
                }
#pragma unroll
                for (int ks = 0; ks < 8; ++ks) {
                    v8s a = *(const v8s*)&sm.u.g.lA[(w * 16 + (lane & 15)) * 264 + ks * 32 + (lane >> 4) * 8];
                    v8s b = *(const v8s*)&sm.u.g.lB[(lane & 15) * 264 + ks * 32 + (lane >> 4) * 8];
                    acc = __builtin_amdgcn_mfma_f32_16x16x32_bf16(a, b, acc, 0, 0, 0);
                }
                __syncthreads();
            }
#pragma unroll
            for (int r = 0; r < 4; ++r) {
                int m = w * 16 + (lane >> 4) * 4 + r;   // = batch
                int n = lane & 15;                      // = hco*4 + gate
                sm.u.g.gbuf[m * 20 + n] = acc[r];
            }
            __syncthreads();
            // LSTM epilogue: thread -> (cb, hc); hidx = bid*4 + hc
            {
                const int hidx = hb + hc;
                float gi = sm.u.g.gbuf[cb * 20 + hc * 4 + 0] + bz[hidx];
                float gf = sm.u.g.gbuf[cb * 20 + hc * 4 + 1] + bz[1024 + hidx];
                float gg = sm.u.g.gbuf[cb * 20 + hc * 4 + 2] + bz[2048 + hidx];
                float go = sm.u.g.gbuf[cb * 20 + hc * 4 + 3] + bz[3072 + hidx];
                float cn = sigm(gf) * creg + sigm(gi) * tanhf(gg);
                float hn = sigm(go) * tanhf(cn);
                creg = cn;
                sm.sm_h[tid] = f2bf(hn);
            }
            __syncthreads();
            if (tid < 128) {        // pack 2 bf16 -> dword; coherent h + normal Hall
                unsigned int lo = (unsigned int)sm.sm_h[2 * tid] |
                                  ((unsigned int)sm.sm_h[2 * tid + 1] << 16);
                int b2 = tid >> 1, hco2 = (tid & 1) * 2;
                unsigned int elem = (unsigned int)(b2 * 1024 + hb + hco2);
                cstoreu((unsigned int*)&hseq[(size_t)(t + 1) * 65536 + elem], lo);
                *(unsigned int*)&Hallb[(size_t)t * 65536 + elem] = lo;
            }
        }
        if (t < 23) { btarget += 256; gbar(barcnt, btarget); }
        // final step: kernel completion flushes Hallb before preds_k
    }
}

// ---------------------------------------------------------------------------
// preds: out = Hall[1536,1024](bf16) @ W_out[10000,1024](f32, converted
// inline)^T + b_out. Tile 128x128, BK=64, reg-dbuf. grid = 960, XCD-aware
// n-strip mapping (strip fetched once per XCD).
// ---------------------------------------------------------------------------
__global__ __launch_bounds__(256) void preds_k(
    const unsigned short* __restrict__ Hall, const float* __restrict__ WoutF,
    const float* __restrict__ bout, float* __restrict__ out)
{
    const int bidl = blockIdx.x;
    const int xcd = bidl & 7, loc = bidl >> 3;
    const int nbi = xcd * 10 + loc / 12;
    const int mbi = loc - (loc / 12) * 12;
    if (nbi >= 79) return;
    __shared__ unsigned short lA[128 * 72];
    __shared__ unsigned short lB[128 * 72];
    const int tid = threadIdx.x, lane = tid & 63, w = tid >> 6;
    const int mb = mbi * 128, nb = nbi * 128;
    const int rT = tid >> 3, cT = (tid & 7) * 8;
    v4f acc[2][8];
#pragma unroll
    for (int i = 0; i < 2; ++i)
#pragma unroll
        for (int f = 0; f < 8; ++f) acc[i][f] = (v4f){0.f, 0.f, 0.f, 0.f};
    v4i ra[4];
    v4f rbf[4][2];
#pragma unroll
    for (int i = 0; i < 4; ++i) {
        ra[i] = *(const v4i*)&Hall[(mb + rT + i * 32) * 1024 + cT];
        int n2 = nb + rT + i * 32; if (n2 > 9999) n2 = 9999;
        const float* src = &WoutF[(size_t)n2 * 1024 + cT];
        rbf[i][0] = *(const v4f*)src; rbf[i][1] = *(const v4f*)(src + 4);
    }
    for (int kt = 0; kt < 1024; kt += 64) {
#pragma unroll
        for (int i = 0; i < 4; ++i) {
            *(v4i*)&lA[(rT + i * 32) * 72 + cT] = ra[i];
            *(v4i*)&lB[(rT + i * 32) * 72 + cT] = pack8((const float*)&rbf[i][0]);
        }
        __syncthreads();
        if (kt + 64 < 1024) {
#pragma unroll
            for (int i = 0; i < 4; ++i) {
                ra[i] = *(const v4i*)&Hall[(mb + rT + i * 32) * 1024 + kt + 64 + cT];
                int n2 = nb + rT + i * 32; if (n2 > 9999) n2 = 9999;
                const float* src = &WoutF[(size_t)n2 * 1024 + kt + 64 + cT];
                rbf[i][0] = *(const v4f*)src; rbf[i][1] = *(const v4f*)(src + 4);
            }
        }
#pragma unroll
        for (int ks = 0; ks < 2; ++ks) {
            int ko = ks * 32 + (lane >> 4) * 8;
            v8s a0 = *(const v8s*)&lA[(w * 32 + (lane & 15)) * 72 + ko];
            v8s a1 = *(const v8s*)&lA[(w * 32 + 16 + (lane & 15)) * 72 + ko];
#pragma unroll
            for (int f = 0; f < 8; ++f) {
                v8s b = *(const v8s*)&lB[(f * 16 + (lane & 15)) * 72 + ko];
                acc[0][f] = __builtin_amdgcn_mfma_f32_16x16x32_bf16(a0, b, acc[0][f], 0, 0, 0);
                acc[1][f] = __builtin_amdgcn_mfma_f32_16x16x32_bf16(a1, b, acc[1][f], 0, 0, 0);
            }
        }
        __syncthreads();
    }
#pragma unroll
    for (int f = 0; f < 8; ++f) {
        int n = nb + f * 16 + (lane & 15);
        if (n < 10000) {
            float bs = bout[n];
#pragma unroll
            for (int i = 0; i < 2; ++i)
#pragma unroll
                for (int r = 0; r < 4; ++r) {
                    int m = mb + w * 32 + i * 16 + (lane >> 4) * 4 + r;
                    int tt = m >> 6, bb = m & 63;
                    out[(bb * 24 + tt) * 10000 + n] = acc[i][f][r] + bs;
                }
        }
    }
}

// ---------------------------------------------------------------------------
extern "C" void kernel_launch(void* const* d_in, const int* in_sizes, int n_in,
                              void* d_out, int out_size, void* d_ws, size_t ws_size,
                              hipStream_t stream)
{
    const float* enc   = (const float*)d_in[0];
    const int*   caps  = (const int*)d_in[1];
    const float* embed = (const float*)d_in[2];
    const float* Weatt = (const float*)d_in[3];
    const float* beatt = (const float*)d_in[4];
    const float* Wdatt = (const float*)d_in[5];
    const float* bdatt = (const float*)d_in[6];
    const float* Wfatt = (const float*)d_in[7];
    const float* bfatt = (const float*)d_in[8];
    const float* Wih   = (const float*)d_in[9];
    const float* bih   = (const float*)d_in[10];
    const float* Whh   = (const float*)d_in[11];
    const float* bhh   = (const float*)d_in[12];
    const float* Wh0   = (const float*)d_in[13];
    const float* bh0   = (const float*)d_in[14];
    const float* Wc0   = (const float*)d_in[15];
    const float* bc0   = (const float*)d_in[16];
    const float* WoutF = (const float*)d_in[17];
    const float* bout  = (const float*)d_in[18];
    float* out = (float*)d_out;

    char* ws = (char*)d_ws;
    size_t off = 0;
    auto carve = [&](size_t bytes) -> void* {
        void* p = ws + off; off += (bytes + 255) & ~(size_t)255; return p;
    };
    // total carve ~53.8 MB (round-6's 79.5 MB may have exceeded ws_size;
    // rounds 0-5 at <=68.1 MB were fine)
    unsigned short* Wzb    = (unsigned short*)carve(11534336ull * 2);
    unsigned short* Weattb = (unsigned short*)carve(655360ull * 2);
    unsigned short* Wdattb = (unsigned short*)carve(524288ull * 2);
    unsigned short* encb   = (unsigned short*)carve(4014080ull * 2);
    unsigned short* embb   = (unsigned short*)carve(786432ull * 2);
    unsigned short* meanb  = (unsigned short*)carve(81920ull * 2);
    unsigned short* att1b  = (unsigned short*)carve(1605632ull * 2);
    unsigned short* Hallb  = (unsigned short*)carve(1572864ull * 2);
    unsigned short* zseq   = (unsigned short*)carve(24ull * 180224 * 2);
    unsigned short* hseq   = (unsigned short*)carve(25ull * 65536 * 2);
    float* bz   = (float*)carve(4096ull * 4);
    float* cst  = (float*)carve(65536ull * 4);
    int*   barcnt = (int*)carve(256);

    // barrier counter must be 0 at loop_k entry every iteration
    hipMemsetAsync(barcnt, 0, 256, stream);

    uber_init<<<8594, 256, 0, stream>>>(Wih, Whh, bih, bhh, Weatt, Wdatt,
        enc, caps, embed, Wzb, Weattb, Wdattb, encb, embb, meanb, bz);

    // h0 -> hseq slot 0 (bf16); c0 -> cst (f32); B read as raw f32
    gemm64_f32B<1><<<64, 256, 0, stream>>>(meanb, 1280, Wh0, 1280, bh0, hseq, 1024);
    gemm64_f32B<0><<<64, 256, 0, stream>>>(meanb, 1280, Wc0, 1280, bc0, cst, 1024);

    gemm_att1_k<<<dim3(8, 49), 256, 0, stream>>>(encb, Weattb, beatt, att1b);

    // 24-step decoder loop: fence-free barriers, rotating z/h buffers
    loop_k<<<256, 256, 0, stream>>>(zseq, Wdattb, bdatt, att1b, Wfatt,
        bfatt, encb, embb, Wzb, bz, cst, Hallb, hseq, barcnt);

    preds_k<<<960, 256, 0, stream>>>(Hallb, WoutF, bout, out);
}

// Round 8
// 2026.906 us; speedup vs baseline: 1.3966x; 1.0619x over previous
//
#include <hip/hip_runtime.h>
#include <hip/hip_bf16.h>

typedef float  v4f __attribute__((ext_vector_type(4)));
typedef short  v8s __attribute__((ext_vector_type(8)));
typedef int    v4i __attribute__((ext_vector_type(4)));

#define DEV static __device__ __forceinline__

DEV float bf2f(unsigned short u) {
    union { unsigned int i; float f; } x; x.i = ((unsigned int)u) << 16; return x.f;
}
DEV unsigned short f2bf(float f) {
    union { float f; unsigned int i; } x; x.f = f;
    unsigned int r = x.i + 0x7fff + ((x.i >> 16) & 1);
    return (unsigned short)(r >> 16);
}
DEV float sigm(float x) { return 1.f / (1.f + __expf(-x)); }

DEV v4i pack8(const float* f) {
    v4i o;
#pragma unroll
    for (int q = 0; q < 4; ++q)
        ((unsigned int*)&o)[q] = (unsigned int)f2bf(f[2 * q]) |
                                 ((unsigned int)f2bf(f[2 * q + 1]) << 16);
    return o;
}
DEV float lo16(unsigned int x) { union { unsigned int i; float f; } u; u.i = x << 16; return u.f; }
DEV float hi16(unsigned int x) { union { unsigned int i; float f; } u; u.i = x & 0xffff0000u; return u.f; }

// Coherent (agent-scope, relaxed) stores: write through to the MALL coherence
// point (validated round 5). Producers of z/h use these; consumers use NORMAL
// cached loads on ROTATING per-step buffers (first-touch per launch).
DEV void cstoreu(unsigned int* p, unsigned int v) {
    __hip_atomic_store(p, v, __ATOMIC_RELAXED, __HIP_MEMORY_SCOPE_AGENT);
}
DEV void cstore4(unsigned short* p, v4i v) {
    unsigned int* q = (unsigned int*)p;
    cstoreu(q,     ((unsigned int*)&v)[0]);
    cstoreu(q + 1, ((unsigned int*)&v)[1]);
    cstoreu(q + 2, ((unsigned int*)&v)[2]);
    cstoreu(q + 3, ((unsigned int*)&v)[3]);
}

// Grid barrier, round-8: two-level arrival + flag-poll exit.
// Round-7 lesson: spinning with RMWs on ONE line saturates its coherence-
// point atomic unit (~50 RMW/us service vs 300/us offered) -> arrival RMWs
// queue behind spinner RMWs -> ~30us/barrier (the 79us/step floor common to
// rounds 3/4/5/7). Fix: arrivals on 8 per-group lines (32 contenders each,
// parallel), roots on their own line (8), completion broadcast via a FLAG
// store; spinners poll the flag with relaxed agent LOADS (read-only, no
// serialization vs arrivals; coherence of relaxed agent loads proven in
// round 5). Monotonic epochs, no resets. No release/acquire anywhere
// (rounds 2-4 lesson: wbl2/inv per barrier cost ~50us).
DEV void gbar(int* bar, int bid, int epoch) {
    __syncthreads();
    if (threadIdx.x == 0) {
        int* grp  = bar + (bid & 7) * 32;   // 8 lines, 128B apart
        int* root = bar + 256;              // own 128B line
        int* flag = bar + 288;              // own 128B line
        int prev = __hip_atomic_fetch_add(grp, 1, __ATOMIC_RELAXED, __HIP_MEMORY_SCOPE_AGENT);
        if (prev + 1 == 32 * epoch) {       // last of this 32-block group
            int rr = __hip_atomic_fetch_add(root, 1, __ATOMIC_RELAXED, __HIP_MEMORY_SCOPE_AGENT);
            if (rr + 1 == 8 * epoch)        // last group -> broadcast epoch
                __hip_atomic_store(flag, epoch, __ATOMIC_RELAXED, __HIP_MEMORY_SCOPE_AGENT);
        }
        while (__hip_atomic_load(flag, __ATOMIC_RELAXED, __HIP_MEMORY_SCOPE_AGENT) < epoch)
            __builtin_amdgcn_s_sleep(32);
        asm volatile("" ::: "memory");
    }
    __syncthreads();
}

// ---------------------------------------------------------------------------
// uber_init: 8 elements per thread. Only converts what the loop needs as
// bf16 (Wz, W_eatt, W_datt, enc, emb gather, mean, bz).
// ---------------------------------------------------------------------------
__global__ __launch_bounds__(256) void uber_init(
    const float* __restrict__ Wih, const float* __restrict__ Whh,
    const float* __restrict__ bih, const float* __restrict__ bhh,
    const float* __restrict__ WeattF, const float* __restrict__ WdattF,
    const float* __restrict__ enc, const int* __restrict__ caps,
    const float* __restrict__ embed,
    unsigned short* __restrict__ Wz, unsigned short* __restrict__ Weattb,
    unsigned short* __restrict__ Wdattb, unsigned short* __restrict__ encb,
    unsigned short* __restrict__ embb, unsigned short* __restrict__ meanb,
    float* __restrict__ bz)
{
    const int i = (blockIdx.x * 256 + threadIdx.x) * 8;
    float f[8];
    if (i < 11534336) {                       // Wz = [W_ih | W_hh] rows of 2816
        int n = i / 2816, k = i - n * 2816;
        const float* src = (k < 1792) ? &Wih[n * 1792 + k] : &Whh[n * 1024 + (k - 1792)];
        *(v4f*)&f[0] = *(const v4f*)src; *(v4f*)&f[4] = *(const v4f*)(src + 4);
        *(v4i*)&Wz[i] = pack8(f);
    } else if (i < 12189696) {                // W_eatt
        int j = i - 11534336;
        *(v4f*)&f[0] = *(const v4f*)&WeattF[j]; *(v4f*)&f[4] = *(const v4f*)&WeattF[j + 4];
        *(v4i*)&Weattb[j] = pack8(f);
    } else if (i < 12713984) {                // W_datt
        int j = i - 12189696;
        *(v4f*)&f[0] = *(const v4f*)&WdattF[j]; *(v4f*)&f[4] = *(const v4f*)&WdattF[j + 4];
        *(v4i*)&Wdattb[j] = pack8(f);
    } else if (i < 16728064) {                // encoder_out
        int j = i - 12713984;
        *(v4f*)&f[0] = *(const v4f*)&enc[j]; *(v4f*)&f[4] = *(const v4f*)&enc[j + 4];
        *(v4i*)&encb[j] = pack8(f);
    } else if (i < 17514496) {                // emb gather (t < 24 only)
        int j = i - 16728064;
        int b = j / 12288, r = j - b * 12288, t = r / 512, e = r - t * 512;
        const float* src = &embed[caps[b * 25 + t] * 512 + e];
        *(v4f*)&f[0] = *(const v4f*)src; *(v4f*)&f[4] = *(const v4f*)(src + 4);
        *(v4i*)&embb[j] = pack8(f);
    } else if (i < 17596416) {                // mean over P=49
        int j = i - 17514496;
        int b = j / 1280, c = j - b * 1280;
#pragma unroll
        for (int q = 0; q < 8; ++q) f[q] = 0.f;
        for (int p = 0; p < 49; ++p) {
            const float* src = &enc[(b * 49 + p) * 1280 + c];
            v4f a = *(const v4f*)src, bq = *(const v4f*)(src + 4);
#pragma unroll
            for (int q = 0; q < 4; ++q) { f[q] += a[q]; f[q + 4] += bq[q]; }
        }
#pragma unroll
        for (int q = 0; q < 8; ++q) f[q] *= (1.f / 49.f);
        *(v4i*)&meanb[j] = pack8(f);
    } else if (i < 17600512) {                // bz = b_ih + b_hh
        int j = i - 17596416;
#pragma unroll
        for (int q = 0; q < 8; ++q) f[q] = bih[j + q] + bhh[j + q];
        *(v4f*)&bz[j] = *(v4f*)&f[0]; *(v4f*)&bz[j + 4] = *(v4f*)&f[4];
    }
}

// ---------------------------------------------------------------------------
// gemm64_f32B: C[64,N] = A[64,K](bf16) @ B[N,K](f32, converted inline)^T + b.
// BN=16 per block. Used for h0/c0 init only.
// ---------------------------------------------------------------------------
template <int OUT_BF16>
__global__ __launch_bounds__(256) void gemm64_f32B(
    const unsigned short* __restrict__ Ag, int lda,
    const float* __restrict__ BgF, int K,
    const float* __restrict__ bias, void* __restrict__ Cg, int ldc)
{
    __shared__ unsigned short lA[64 * 264];
    __shared__ unsigned short lB[16 * 264];
    const int tid = threadIdx.x, lane = tid & 63, w = tid >> 6;
    const int nb = blockIdx.x * 16;
    const int rA = tid >> 5, cA = (tid & 31) * 8;
    v4f acc = {0.f, 0.f, 0.f, 0.f};
    v4i ra[8];
    v4f rbf[2][2];
#pragma unroll
    for (int i = 0; i < 8; ++i)
        ra[i] = *(const v4i*)&Ag[(rA + i * 8) * lda + cA];
#pragma unroll
    for (int i = 0; i < 2; ++i) {
        const float* src = &BgF[(size_t)(nb + rA + i * 8) * K + cA];
        rbf[i][0] = *(const v4f*)src; rbf[i][1] = *(const v4f*)(src + 4);
    }
    for (int kt = 0; kt < K; kt += 256) {
#pragma unroll
        for (int i = 0; i < 8; ++i) *(v4i*)&lA[(rA + i * 8) * 264 + cA] = ra[i];
#pragma unroll
        for (int i = 0; i < 2; ++i)
            *(v4i*)&lB[(rA + i * 8) * 264 + cA] = pack8((const float*)&rbf[i][0]);
        __syncthreads();
        if (kt + 256 < K) {
#pragma unroll
            for (int i = 0; i < 8; ++i)
                ra[i] = *(const v4i*)&Ag[(rA + i * 8) * lda + kt + 256 + cA];
#pragma unroll
            for (int i = 0; i < 2; ++i) {
                const float* src = &BgF[(size_t)(nb + rA + i * 8) * K + kt + 256 + cA];
                rbf[i][0] = *(const v4f*)src; rbf[i][1] = *(const v4f*)(src + 4);
            }
        }
#pragma unroll
        for (int ks = 0; ks < 8; ++ks) {
            v8s a = *(const v8s*)&lA[(w * 16 + (lane & 15)) * 264 + ks * 32 + (lane >> 4) * 8];
            v8s b = *(const v8s*)&lB[(lane & 15) * 264 + ks * 32 + (lane >> 4) * 8];
            acc = __builtin_amdgcn_mfma_f32_16x16x32_bf16(a, b, acc, 0, 0, 0);
        }
        __syncthreads();
    }
    const int n = nb + (lane & 15);
    const float bs = bias[n];
#pragma unroll
    for (int r = 0; r < 4; ++r) {
        int m = w * 16 + (lane >> 4) * 4 + r;
        float v = acc[r] + bs;
        if (OUT_BF16) ((unsigned short*)Cg)[m * ldc + n] = f2bf(v);
        else          ((float*)Cg)[m * ldc + n] = v;
    }
}

// ---------------------------------------------------------------------------
// gemm_att1: att1[3136,512](bf16) = enc_b[3136,1280] @ W_eatt[512,1280]^T + b
// ---------------------------------------------------------------------------
__global__ __launch_bounds__(256) void gemm_att1_k(
    const unsigned short* __restrict__ Aenc, const unsigned short* __restrict__ Bw,
    const float* __restrict__ bias, unsigned short* __restrict__ Cout)
{
    __shared__ unsigned short lA[64 * 136];
    __shared__ unsigned short lB[64 * 136];
    const int tid = threadIdx.x, lane = tid & 63, w = tid >> 6;
    const int mb = blockIdx.y * 64, nb = blockIdx.x * 64;
    const int rT = tid >> 4, cT = (tid & 15) * 8;
    v4f acc[4];
#pragma unroll
    for (int f = 0; f < 4; ++f) acc[f] = (v4f){0.f, 0.f, 0.f, 0.f};
    v4i ra[4], rb[4];
#pragma unroll
    for (int i = 0; i < 4; ++i) {
        ra[i] = *(const v4i*)&Aenc[(mb + rT + i * 16) * 1280 + cT];
        rb[i] = *(const v4i*)&Bw[(nb + rT + i * 16) * 1280 + cT];
    }
    for (int kt = 0; kt < 1280; kt += 128) {
#pragma unroll
        for (int i = 0; i < 4; ++i) {
            *(v4i*)&lA[(rT + i * 16) * 136 + cT] = ra[i];
            *(v4i*)&lB[(rT + i * 16) * 136 + cT] = rb[i];
        }
        __syncthreads();
        if (kt + 128 < 1280) {
#pragma unroll
            for (int i = 0; i < 4; ++i) {
                ra[i] = *(const v4i*)&Aenc[(mb + rT + i * 16) * 1280 + kt + 128 + cT];
                rb[i] = *(const v4i*)&Bw[(nb + rT + i * 16) * 1280 + kt + 128 + cT];
            }
        }
#pragma unroll
        for (int ks = 0; ks < 4; ++ks) {
            v8s a = *(const v8s*)&lA[(w * 16 + (lane & 15)) * 136 + ks * 32 + (lane >> 4) * 8];
#pragma unroll
            for (int f = 0; f < 4; ++f) {
                v8s b = *(const v8s*)&lB[(f * 16 + (lane & 15)) * 136 + ks * 32 + (lane >> 4) * 8];
                acc[f] = __builtin_amdgcn_mfma_f32_16x16x32_bf16(a, b, acc[f], 0, 0, 0);
            }
        }
        __syncthreads();
    }
#pragma unroll
    for (int f = 0; f < 4; ++f) {
        int n = nb + f * 16 + (lane & 15);
        float bs = bias[f >= 0 ? n : n];
        bs = bias[n];
#pragma unroll
        for (int r = 0; r < 4; ++r) {
            int m = mb + w * 16 + (lane >> 4) * 4 + r;
            Cout[m * 512 + n] = f2bf(acc[f][r] + bs);
        }
    }
}

// ---------------------------------------------------------------------------
// loop_k: 24-step decoder loop. grid = 256 blocks x 256 threads, 47.9 KB LDS
// -> 3 blocks/CU capacity (768 >= 256, co-residency margin). Rotating z/h
// buffers: producers use coherent MALL stores, consumers use normal cached
// loads (first-touch per slot). Read-only data stays L2-warm all 24 steps.
//   phaseA (blocks 0..63, block b): att2 GEMV in LDS + scores/softmax/ctx;
//     writes z[t] row b = [emb | ctx | h[t] row b].
//   phaseB (all 256, block j): gates[64 x 16] for h-cols [4j,4j+4) x 4 gates,
//     K=2816 MFMA GEMM; LSTM epilogue -> h[t+1] (coherent) + Hall (normal).
//   c-state in registers.
// ---------------------------------------------------------------------------
struct SmemGemm {
    unsigned short lA[64 * 264];
    unsigned short lB[16 * 264];
    float gbuf[64 * 20];
};
struct SmemAttn {
    float a2[512];
    float wf[512];
    float hf[1024];
    float es[64];
    float alpha[64];
};
struct LoopSmem {
    union { SmemGemm g; SmemAttn a; } u;     // 47360 B
    unsigned short sm_h[256];                //   512 B
};                                           // 47872 B -> 3 blocks/CU

__global__ __launch_bounds__(256, 1) void loop_k(
    unsigned short* __restrict__ zseq,        // 24 x [64][2816]
    const unsigned short* __restrict__ Wdattb, const float* __restrict__ bdatt,
    const unsigned short* __restrict__ att1b, const float* __restrict__ Wfatt,
    const float* __restrict__ bfatt, const unsigned short* __restrict__ encb,
    const unsigned short* __restrict__ embb, const unsigned short* __restrict__ Wzb,
    const float* __restrict__ bz, const float* __restrict__ cst,
    unsigned short* __restrict__ Hallb,
    unsigned short* __restrict__ hseq,        // 25 x [64][1024]; slot 0 = h0
    int* __restrict__ barcnt)
{
    __shared__ LoopSmem sm;
    const int tid = threadIdx.x, lane = tid & 63, w = tid >> 6;
    const int bid = blockIdx.x;          // 0..255
    int ep = 0;

    // registerized c-state: block bid owns h-cols [bid*4, bid*4+4)
    const int cb = tid >> 2, hc = tid & 3;
    float creg = cst[cb * 1024 + bid * 4 + hc];

    for (int t = 0; t < 24; ++t) {
        unsigned short* zt = zseq + t * 180224;
        const unsigned short* ht = hseq + t * 65536;

        // ============ phaseA: GEMV att2 + attention + z assembly (blocks 0..63)
        if (bid < 64) {
            const int b = bid;
            float* a2 = sm.u.a.a2; float* wf = sm.u.a.wf; float* hf = sm.u.a.hf;
            float* es = sm.u.a.es; float* alpha = sm.u.a.alpha;
            if (tid < 128) {
                v4i u = *(const v4i*)&ht[b * 1024 + tid * 8];   // normal (first touch)
                cstore4(&zt[b * 2816 + 1792 + tid * 8], u);     // z h-columns
#pragma unroll
                for (int q = 0; q < 4; ++q) {
                    unsigned int x = ((unsigned int*)&u)[q];
                    hf[tid * 8 + 2 * q]     = lo16(x);
                    hf[tid * 8 + 2 * q + 1] = hi16(x);
                }
            }
            wf[tid]       = Wfatt[tid];
            wf[tid + 256] = Wfatt[tid + 256];
            if (tid < 64) {                                     // z emb-columns
                v4i u = *(const v4i*)&embb[(b * 24 + t) * 512 + tid * 8];
                cstore4(&zt[b * 2816 + tid * 8], u);
            }
            __syncthreads();
            // GEMV: thread computes att2 outputs n=tid and n=tid+256.
            {
                const unsigned short* w0 = &Wdattb[(size_t)tid * 1024];
                const unsigned short* w1 = &Wdattb[(size_t)(tid + 256) * 1024];
                float s0 = 0.f, s1 = 0.f, s2 = 0.f, s3 = 0.f;
                for (int k = 0; k < 1024; k += 8) {
                    v4i u0 = *(const v4i*)&w0[k];
                    v4i u1 = *(const v4i*)&w1[k];
#pragma unroll
                    for (int q = 0; q < 4; ++q) {
                        unsigned int x0 = ((unsigned int*)&u0)[q];
                        unsigned int x1 = ((unsigned int*)&u1)[q];
                        float ha = hf[k + 2 * q], hb2 = hf[k + 2 * q + 1];
                        s0 += lo16(x0) * ha; s1 += hi16(x0) * hb2;
                        s2 += lo16(x1) * ha; s3 += hi16(x1) * hb2;
                    }
                }
                a2[tid]       = s0 + s1 + bdatt[tid];
                a2[tid + 256] = s2 + s3 + bdatt[tid + 256];
            }
            __syncthreads();
            // scores
            for (int p = w; p < 49; p += 4) {
                v4i u = *(const v4i*)&att1b[(b * 49 + p) * 512 + lane * 8];
                v4f c0 = *(const v4f*)&a2[lane * 8], c1 = *(const v4f*)&a2[lane * 8 + 4];
                v4f w0 = *(const v4f*)&wf[lane * 8], w1 = *(const v4f*)&wf[lane * 8 + 4];
                float s = 0.f;
#pragma unroll
                for (int q = 0; q < 4; ++q) {
                    unsigned int x = ((unsigned int*)&u)[q];
                    float vlo = lo16(x), vhi = hi16(x);
                    float clo = (q < 2) ? c0[q * 2] : c1[q * 2 - 4];
                    float chi = (q < 2) ? c0[q * 2 + 1] : c1[q * 2 - 3];
                    float wlo = (q < 2) ? w0[q * 2] : w1[q * 2 - 4];
                    float whi = (q < 2) ? w0[q * 2 + 1] : w1[q * 2 - 3];
                    s += fmaxf(vlo + clo, 0.f) * wlo;
                    s += fmaxf(vhi + chi, 0.f) * whi;
                }
#pragma unroll
                for (int off = 32; off > 0; off >>= 1) s += __shfl_xor(s, off);
                if (lane == 0) es[p] = s + bfatt[0];
            }
            __syncthreads();
            if (w == 0) {
                float v = (lane < 49) ? es[lane] : -1e30f;
                float m = v;
#pragma unroll
                for (int off = 32; off > 0; off >>= 1) m = fmaxf(m, __shfl_xor(m, off));
                float e = (lane < 49) ? __expf(v - m) : 0.f;
                float s = e;
#pragma unroll
                for (int off = 32; off > 0; off >>= 1) s += __shfl_xor(s, off);
                if (lane < 49) alpha[lane] = e / s;
            }
            __syncthreads();
            if (tid < 160) {                                    // z ctx-columns
                const int jb = tid * 8;
                float acc[8];
#pragma unroll
                for (int q = 0; q < 8; ++q) acc[q] = 0.f;
                for (int p = 0; p < 49; ++p) {
                    v4i u = *(const v4i*)&encb[(b * 49 + p) * 1280 + jb];
                    float al = alpha[p];
#pragma unroll
                    for (int q = 0; q < 4; ++q) {
                        unsigned int x = ((unsigned int*)&u)[q];
                        acc[2 * q]     += al * lo16(x);
                        acc[2 * q + 1] += al * hi16(x);
                    }
                }
                cstore4(&zt[b * 2816 + 512 + jb], pack8(acc));
            }
        }
        ++ep; gbar(barcnt, bid, ep);

        // ============ phaseB: gates GEMM + LSTM epilogue (all 256 blocks)
        {
            const int hb = bid * 4;
            const int rT = tid >> 5, cT = (tid & 31) * 8;
            const int gate = rT & 3, hco = rT >> 2;
            const int growB  = (gate * 1024 + hb + hco) * 2816;
            const int growB2 = (((rT + 8) & 3) * 1024 + hb + ((rT + 8) >> 2)) * 2816;
            v4f acc = {0.f, 0.f, 0.f, 0.f};
            v4i ra[8], rb[2];
#pragma unroll
            for (int i = 0; i < 8; ++i)
                ra[i] = *(const v4i*)&zt[(rT + i * 8) * 2816 + cT];   // normal load
            rb[0] = *(const v4i*)&Wzb[growB + cT];
            rb[1] = *(const v4i*)&Wzb[growB2 + cT];
            for (int kt = 0; kt < 2816; kt += 256) {
#pragma unroll
                for (int i = 0; i < 8; ++i) *(v4i*)&sm.u.g.lA[(rT + i * 8) * 264 + cT] = ra[i];
                *(v4i*)&sm.u.g.lB[rT * 264 + cT] = rb[0];
                *(v4i*)&sm.u.g.lB[(rT + 8) * 264 + cT] = rb[1];
                __syncthreads();
                if (kt + 256 < 2816) {
#pragma unroll
                    for (int i = 0; i < 8; ++i)
                        ra[i] = *(const v4i*)&zt[(rT + i * 8) * 2816 + kt + 256 + cT];
                    rb[0] = *(const v4i*)&Wzb[growB + kt + 256 + cT];
                    rb[1] = *(const v4i*)&Wzb[growB2 + kt + 256 + cT];
                }
#pragma unroll
                for (int ks = 0; ks < 8; ++ks) {
                    v8s a = *(const v8s*)&sm.u.g.lA[(w * 16 + (lane & 15)) * 264 + ks * 32 + (lane >> 4) * 8];
                    v8s b = *(const v8s*)&sm.u.g.lB[(lane & 15) * 264 + ks * 32 + (lane >> 4) * 8];
                    acc = __builtin_amdgcn_mfma_f32_16x16x32_bf16(a, b, acc, 0, 0, 0);
                }
                __syncthreads();
            }
#pragma unroll
            for (int r = 0; r < 4; ++r) {
                int m = w * 16 + (lane >> 4) * 4 + r;   // = batch
                int n = lane & 15;                      // = hco*4 + gate
                sm.u.g.gbuf[m * 20 + n] = acc[r];
            }
            __syncthreads();
            // LSTM epilogue: thread -> (cb, hc); hidx = bid*4 + hc
            {
                const int hidx = hb + hc;
                float gi = sm.u.g.gbuf[cb * 20 + hc * 4 + 0] + bz[hidx];
                float gf = sm.u.g.gbuf[cb * 20 + hc * 4 + 1] + bz[1024 + hidx];
                float gg = sm.u.g.gbuf[cb * 20 + hc * 4 + 2] + bz[2048 + hidx];
                float go = sm.u.g.gbuf[cb * 20 + hc * 4 + 3] + bz[3072 + hidx];
                float cn = sigm(gf) * creg + sigm(gi) * tanhf(gg);
                float hn = sigm(go) * tanhf(cn);
                creg = cn;
                sm.sm_h[tid] = f2bf(hn);
            }
            __syncthreads();
            if (tid < 128) {        // pack 2 bf16 -> dword; coherent h + normal Hall
                unsigned int lo = (unsigned int)sm.sm_h[2 * tid] |
                                  ((unsigned int)sm.sm_h[2 * tid + 1] << 16);
                int b2 = tid >> 1, hco2 = (tid & 1) * 2;
                unsigned int elem = (unsigned int)(b2 * 1024 + hb + hco2);
                cstoreu((unsigned int*)&hseq[(size_t)(t + 1) * 65536 + elem], lo);
                *(unsigned int*)&Hallb[(size_t)t * 65536 + elem] = lo;
            }
        }
        if (t < 23) { ++ep; gbar(barcnt, bid, ep); }
        // final step: kernel completion flushes Hallb before preds_k
    }
}

// ---------------------------------------------------------------------------
// preds: out = Hall[1536,1024](bf16) @ W_out[10000,1024](f32, inline-cvt)^T
// + b_out. Tile 128x128, BK=64, reg-dbuf. grid = 960, XCD-aware mapping.
// ---------------------------------------------------------------------------
__global__ __launch_bounds__(256) void preds_k(
    const unsigned short* __restrict__ Hall, const float* __restrict__ WoutF,
    const float* __restrict__ bout, float* __restrict__ out)
{
    const int bidl = blockIdx.x;
    const int xcd = bidl & 7, loc = bidl >> 3;
    const int nbi = xcd * 10 + loc / 12;
    const int mbi = loc - (loc / 12) * 12;
    if (nbi >= 79) return;
    __shared__ unsigned short lA[128 * 72];
    __shared__ unsigned short lB[128 * 72];
    const int tid = threadIdx.x, lane = tid & 63, w = tid >> 6;
    const int mb = mbi * 128, nb = nbi * 128;
    const int rT = tid >> 3, cT = (tid & 7) * 8;
    v4f acc[2][8];
#pragma unroll
    for (int i = 0; i < 2; ++i)
#pragma unroll
        for (int f = 0; f < 8; ++f) acc[i][f] = (v4f){0.f, 0.f, 0.f, 0.f};
    v4i ra[4];
    v4f rbf[4][2];
#pragma unroll
    for (int i = 0; i < 4; ++i) {
        ra[i] = *(const v4i*)&Hall[(mb + rT + i * 32) * 1024 + cT];
        int n2 = nb + rT + i * 32; if (n2 > 9999) n2 = 9999;
        const float* src = &WoutF[(size_t)n2 * 1024 + cT];
        rbf[i][0] = *(const v4f*)src; rbf[i][1] = *(const v4f*)(src + 4);
    }
    for (int kt = 0; kt < 1024; kt += 64) {
#pragma unroll
        for (int i = 0; i < 4; ++i) {
            *(v4i*)&lA[(rT + i * 32) * 72 + cT] = ra[i];
            *(v4i*)&lB[(rT + i * 32) * 72 + cT] = pack8((const float*)&rbf[i][0]);
        }
        __syncthreads();
        if (kt + 64 < 1024) {
#pragma unroll
            for (int i = 0; i < 4; ++i) {
                ra[i] = *(const v4i*)&Hall[(mb + rT + i * 32) * 1024 + kt + 64 + cT];
                int n2 = nb + rT + i * 32; if (n2 > 9999) n2 = 9999;
                const float* src = &WoutF[(size_t)n2 * 1024 + kt + 64 + cT];
                rbf[i][0] = *(const v4f*)src; rbf[i][1] = *(const v4f*)(src + 4);
            }
        }
#pragma unroll
        for (int ks = 0; ks < 2; ++ks) {
            int ko = ks * 32 + (lane >> 4) * 8;
            v8s a0 = *(const v8s*)&lA[(w * 32 + (lane & 15)) * 72 + ko];
            v8s a1 = *(const v8s*)&lA[(w * 32 + 16 + (lane & 15)) * 72 + ko];
#pragma unroll
            for (int f = 0; f < 8; ++f) {
                v8s b = *(const v8s*)&lB[(f * 16 + (lane & 15)) * 72 + ko];
                acc[0][f] = __builtin_amdgcn_mfma_f32_16x16x32_bf16(a0, b, acc[0][f], 0, 0, 0);
                acc[1][f] = __builtin_amdgcn_mfma_f32_16x16x32_bf16(a1, b, acc[1][f], 0, 0, 0);
            }
        }
        __syncthreads();
    }
#pragma unroll
    for (int f = 0; f < 8; ++f) {
        int n = nb + f * 16 + (lane & 15);
        if (n < 10000) {
            float bs = bout[n];
#pragma unroll
            for (int i = 0; i < 2; ++i)
#pragma unroll
                for (int r = 0; r < 4; ++r) {
                    int m = mb + w * 32 + i * 16 + (lane >> 4) * 4 + r;
                    int tt = m >> 6, bb = m & 63;
                    out[(bb * 24 + tt) * 10000 + n] = acc[i][f][r] + bs;
                }
        }
    }
}

// ---------------------------------------------------------------------------
extern "C" void kernel_launch(void* const* d_in, const int* in_sizes, int n_in,
                              void* d_out, int out_size, void* d_ws, size_t ws_size,
                              hipStream_t stream)
{
    const float* enc   = (const float*)d_in[0];
    const int*   caps  = (const int*)d_in[1];
    const float* embed = (const float*)d_in[2];
    const float* Weatt = (const float*)d_in[3];
    const float* beatt = (const float*)d_in[4];
    const float* Wdatt = (const float*)d_in[5];
    const float* bdatt = (const float*)d_in[6];
    const float* Wfatt = (const float*)d_in[7];
    const float* bfatt = (const float*)d_in[8];
    const float* Wih   = (const float*)d_in[9];
    const float* bih   = (const float*)d_in[10];
    const float* Whh   = (const float*)d_in[11];
    const float* bhh   = (const float*)d_in[12];
    const float* Wh0   = (const float*)d_in[13];
    const float* bh0   = (const float*)d_in[14];
    const float* Wc0   = (const float*)d_in[15];
    const float* bc0   = (const float*)d_in[16];
    const float* WoutF = (const float*)d_in[17];
    const float* bout  = (const float*)d_in[18];
    float* out = (float*)d_out;

    char* ws = (char*)d_ws;
    size_t off = 0;
    auto carve = [&](size_t bytes) -> void* {
        void* p = ws + off; off += (bytes + 255) & ~(size_t)255; return p;
    };
    // total carve ~53.8 MB (round-7-validated budget)
    unsigned short* Wzb    = (unsigned short*)carve(11534336ull * 2);
    unsigned short* Weattb = (unsigned short*)carve(655360ull * 2);
    unsigned short* Wdattb = (unsigned short*)carve(524288ull * 2);
    unsigned short* encb   = (unsigned short*)carve(4014080ull * 2);
    unsigned short* embb   = (unsigned short*)carve(786432ull * 2);
    unsigned short* meanb  = (unsigned short*)carve(81920ull * 2);
    unsigned short* att1b  = (unsigned short*)carve(1605632ull * 2);
    unsigned short* Hallb  = (unsigned short*)carve(1572864ull * 2);
    unsigned short* zseq   = (unsigned short*)carve(24ull * 180224 * 2);
    unsigned short* hseq   = (unsigned short*)carve(25ull * 65536 * 2);
    float* bz   = (float*)carve(4096ull * 4);
    float* cst  = (float*)carve(65536ull * 4);
    int*   barcnt = (int*)carve(2048);     // 8 group lines + root + flag

    // barrier counters must be 0 at loop_k entry every iteration
    hipMemsetAsync(barcnt, 0, 2048, stream);

    uber_init<<<8594, 256, 0, stream>>>(Wih, Whh, bih, bhh, Weatt, Wdatt,
        enc, caps, embed, Wzb, Weattb, Wdattb, encb, embb, meanb, bz);

    // h0 -> hseq slot 0 (bf16); c0 -> cst (f32); B read as raw f32
    gemm64_f32B<1><<<64, 256, 0, stream>>>(meanb, 1280, Wh0, 1280, bh0, hseq, 1024);
    gemm64_f32B<0><<<64, 256, 0, stream>>>(meanb, 1280, Wc0, 1280, bc0, cst, 1024);

    gemm_att1_k<<<dim3(8, 49), 256, 0, stream>>>(encb, Weattb, beatt, att1b);

    // 24-step decoder loop: two-level flag barrier, rotating z/h buffers
    loop_k<<<256, 256, 0, stream>>>(zseq, Wdattb, bdatt, att1b, Wfatt,
        bfatt, encb, embb, Wzb, bz, cst, Hallb, hseq, barcnt);

    preds_k<<<960, 256, 0, stream>>>(Hallb, WoutF, bout, out);
}

// Round 9
// 1286.904 us; speedup vs baseline: 2.1996x; 1.5750x over previous
//
#include <hip/hip_runtime.h>
#include <hip/hip_bf16.h>

typedef float  v4f __attribute__((ext_vector_type(4)));
typedef short  v8s __attribute__((ext_vector_type(8)));
typedef int    v4i __attribute__((ext_vector_type(4)));

#define DEV static __device__ __forceinline__

DEV float bf2f(unsigned short u) {
    union { unsigned int i; float f; } x; x.i = ((unsigned int)u) << 16; return x.f;
}
DEV unsigned short f2bf(float f) {
    union { float f; unsigned int i; } x; x.f = f;
    unsigned int r = x.i + 0x7fff + ((x.i >> 16) & 1);
    return (unsigned short)(r >> 16);
}
DEV float sigm(float x) { return 1.f / (1.f + __expf(-x)); }
DEV unsigned int fbits(float f) { union { float f; unsigned int u; } x; x.f = f; return x.u; }

DEV v4i pack8(const float* f) {
    v4i o;
#pragma unroll
    for (int q = 0; q < 4; ++q)
        ((unsigned int*)&o)[q] = (unsigned int)f2bf(f[2 * q]) |
                                 ((unsigned int)f2bf(f[2 * q + 1]) << 16);
    return o;
}
DEV float lo16(unsigned int x) { union { unsigned int i; float f; } u; u.i = x << 16; return u.f; }
DEV float hi16(unsigned int x) { union { unsigned int i; float f; } u; u.i = x & 0xffff0000u; return u.f; }

// Coherent (agent-scope, relaxed) stores: write through to the MALL coherence
// point (validated round 5). Producers of z/h/att2 use these; consumers use
// NORMAL cached loads on ROTATING per-step buffers (first-touch per launch).
DEV void cstoreu(unsigned int* p, unsigned int v) {
    __hip_atomic_store(p, v, __ATOMIC_RELAXED, __HIP_MEMORY_SCOPE_AGENT);
}
DEV void cstore4(unsigned short* p, v4i v) {
    unsigned int* q = (unsigned int*)p;
    cstoreu(q,     ((unsigned int*)&v)[0]);
    cstoreu(q + 1, ((unsigned int*)&v)[1]);
    cstoreu(q + 2, ((unsigned int*)&v)[2]);
    cstoreu(q + 3, ((unsigned int*)&v)[3]);
}

// Grid barrier: two-level arrival (8 group lines + root) + flag-poll exit
// (round-8, measured ~2.5us/barrier). Relaxed everywhere; no wbl2/inv.
DEV void gbar(int* bar, int bid, int epoch) {
    __syncthreads();
    if (threadIdx.x == 0) {
        int* grp  = bar + (bid & 7) * 32;   // 8 lines, 128B apart
        int* root = bar + 256;              // own 128B line
        int* flag = bar + 288;              // own 128B line
        int prev = __hip_atomic_fetch_add(grp, 1, __ATOMIC_RELAXED, __HIP_MEMORY_SCOPE_AGENT);
        if (prev + 1 == 32 * epoch) {
            int rr = __hip_atomic_fetch_add(root, 1, __ATOMIC_RELAXED, __HIP_MEMORY_SCOPE_AGENT);
            if (rr + 1 == 8 * epoch)
                __hip_atomic_store(flag, epoch, __ATOMIC_RELAXED, __HIP_MEMORY_SCOPE_AGENT);
        }
        while (__hip_atomic_load(flag, __ATOMIC_RELAXED, __HIP_MEMORY_SCOPE_AGENT) < epoch)
            __builtin_amdgcn_s_sleep(16);
        asm volatile("" ::: "memory");
    }
    __syncthreads();
}

// ---------------------------------------------------------------------------
// uber_init: 8 elements per thread. Converts Wz, W_eatt, W_datt, enc, emb
// gather, mean, bz to bf16 workspace.
// ---------------------------------------------------------------------------
__global__ __launch_bounds__(256) void uber_init(
    const float* __restrict__ Wih, const float* __restrict__ Whh,
    const float* __restrict__ bih, const float* __restrict__ bhh,
    const float* __restrict__ WeattF, const float* __restrict__ WdattF,
    const float* __restrict__ enc, const int* __restrict__ caps,
    const float* __restrict__ embed,
    unsigned short* __restrict__ Wz, unsigned short* __restrict__ Weattb,
    unsigned short* __restrict__ Wdattb, unsigned short* __restrict__ encb,
    unsigned short* __restrict__ embb, unsigned short* __restrict__ meanb,
    float* __restrict__ bz)
{
    const int i = (blockIdx.x * 256 + threadIdx.x) * 8;
    float f[8];
    if (i < 11534336) {                       // Wz = [W_ih | W_hh] rows of 2816
        int n = i / 2816, k = i - n * 2816;
        const float* src = (k < 1792) ? &Wih[n * 1792 + k] : &Whh[n * 1024 + (k - 1792)];
        *(v4f*)&f[0] = *(const v4f*)src; *(v4f*)&f[4] = *(const v4f*)(src + 4);
        *(v4i*)&Wz[i] = pack8(f);
    } else if (i < 12189696) {                // W_eatt
        int j = i - 11534336;
        *(v4f*)&f[0] = *(const v4f*)&WeattF[j]; *(v4f*)&f[4] = *(const v4f*)&WeattF[j + 4];
        *(v4i*)&Weattb[j] = pack8(f);
    } else if (i < 12713984) {                // W_datt
        int j = i - 12189696;
        *(v4f*)&f[0] = *(const v4f*)&WdattF[j]; *(v4f*)&f[4] = *(const v4f*)&WdattF[j + 4];
        *(v4i*)&Wdattb[j] = pack8(f);
    } else if (i < 16728064) {                // encoder_out
        int j = i - 12713984;
        *(v4f*)&f[0] = *(const v4f*)&enc[j]; *(v4f*)&f[4] = *(const v4f*)&enc[j + 4];
        *(v4i*)&encb[j] = pack8(f);
    } else if (i < 17514496) {                // emb gather (t < 24 only)
        int j = i - 16728064;
        int b = j / 12288, r = j - b * 12288, t = r / 512, e = r - t * 512;
        const float* src = &embed[caps[b * 25 + t] * 512 + e];
        *(v4f*)&f[0] = *(const v4f*)src; *(v4f*)&f[4] = *(const v4f*)(src + 4);
        *(v4i*)&embb[j] = pack8(f);
    } else if (i < 17596416) {                // mean over P=49
        int j = i - 17514496;
        int b = j / 1280, c = j - b * 1280;
#pragma unroll
        for (int q = 0; q < 8; ++q) f[q] = 0.f;
        for (int p = 0; p < 49; ++p) {
            const float* src = &enc[(b * 49 + p) * 1280 + c];
            v4f a = *(const v4f*)src, bq = *(const v4f*)(src + 4);
#pragma unroll
            for (int q = 0; q < 4; ++q) { f[q] += a[q]; f[q + 4] += bq[q]; }
        }
#pragma unroll
        for (int q = 0; q < 8; ++q) f[q] *= (1.f / 49.f);
        *(v4i*)&meanb[j] = pack8(f);
    } else if (i < 17600512) {                // bz = b_ih + b_hh
        int j = i - 17596416;
#pragma unroll
        for (int q = 0; q < 8; ++q) f[q] = bih[j + q] + bhh[j + q];
        *(v4f*)&bz[j] = *(v4f*)&f[0]; *(v4f*)&bz[j + 4] = *(v4f*)&f[4];
    }
}

// ---------------------------------------------------------------------------
// gemm64_f32B: C[64,N] = A[64,K](bf16) @ B[N,K](f32, converted inline)^T + b.
// BN=16 per block. Used for h0/c0 init only.
// ---------------------------------------------------------------------------
template <int OUT_BF16>
__global__ __launch_bounds__(256) void gemm64_f32B(
    const unsigned short* __restrict__ Ag, int lda,
    const float* __restrict__ BgF, int K,
    const float* __restrict__ bias, void* __restrict__ Cg, int ldc)
{
    __shared__ unsigned short lA[64 * 264];
    __shared__ unsigned short lB[16 * 264];
    const int tid = threadIdx.x, lane = tid & 63, w = tid >> 6;
    const int nb = blockIdx.x * 16;
    const int rA = tid >> 5, cA = (tid & 31) * 8;
    v4f acc = {0.f, 0.f, 0.f, 0.f};
    v4i ra[8];
    v4f rbf[2][2];
#pragma unroll
    for (int i = 0; i < 8; ++i)
        ra[i] = *(const v4i*)&Ag[(rA + i * 8) * lda + cA];
#pragma unroll
    for (int i = 0; i < 2; ++i) {
        const float* src = &BgF[(size_t)(nb + rA + i * 8) * K + cA];
        rbf[i][0] = *(const v4f*)src; rbf[i][1] = *(const v4f*)(src + 4);
    }
    for (int kt = 0; kt < K; kt += 256) {
#pragma unroll
        for (int i = 0; i < 8; ++i) *(v4i*)&lA[(rA + i * 8) * 264 + cA] = ra[i];
#pragma unroll
        for (int i = 0; i < 2; ++i)
            *(v4i*)&lB[(rA + i * 8) * 264 + cA] = pack8((const float*)&rbf[i][0]);
        __syncthreads();
        if (kt + 256 < K) {
#pragma unroll
            for (int i = 0; i < 8; ++i)
                ra[i] = *(const v4i*)&Ag[(rA + i * 8) * lda + kt + 256 + cA];
#pragma unroll
            for (int i = 0; i < 2; ++i) {
                const float* src = &BgF[(size_t)(nb + rA + i * 8) * K + kt + 256 + cA];
                rbf[i][0] = *(const v4f*)src; rbf[i][1] = *(const v4f*)(src + 4);
            }
        }
#pragma unroll
        for (int ks = 0; ks < 8; ++ks) {
            v8s a = *(const v8s*)&lA[(w * 16 + (lane & 15)) * 264 + ks * 32 + (lane >> 4) * 8];
            v8s b = *(const v8s*)&lB[(lane & 15) * 264 + ks * 32 + (lane >> 4) * 8];
            acc = __builtin_amdgcn_mfma_f32_16x16x32_bf16(a, b, acc, 0, 0, 0);
        }
        __syncthreads();
    }
    const int n = nb + (lane & 15);
    const float bs = bias[n];
#pragma unroll
    for (int r = 0; r < 4; ++r) {
        int m = w * 16 + (lane >> 4) * 4 + r;
        float v = acc[r] + bs;
        if (OUT_BF16) ((unsigned short*)Cg)[m * ldc + n] = f2bf(v);
        else          ((float*)Cg)[m * ldc + n] = v;
    }
}

// ---------------------------------------------------------------------------
// gemm_att1: att1[3136,512](bf16) = enc_b[3136,1280] @ W_eatt[512,1280]^T + b
// ---------------------------------------------------------------------------
__global__ __launch_bounds__(256) void gemm_att1_k(
    const unsigned short* __restrict__ Aenc, const unsigned short* __restrict__ Bw,
    const float* __restrict__ bias, unsigned short* __restrict__ Cout)
{
    __shared__ unsigned short lA[64 * 136];
    __shared__ unsigned short lB[64 * 136];
    const int tid = threadIdx.x, lane = tid & 63, w = tid >> 6;
    const int mb = blockIdx.y * 64, nb = blockIdx.x * 64;
    const int rT = tid >> 4, cT = (tid & 15) * 8;
    v4f acc[4];
#pragma unroll
    for (int f = 0; f < 4; ++f) acc[f] = (v4f){0.f, 0.f, 0.f, 0.f};
    v4i ra[4], rb[4];
#pragma unroll
    for (int i = 0; i < 4; ++i) {
        ra[i] = *(const v4i*)&Aenc[(mb + rT + i * 16) * 1280 + cT];
        rb[i] = *(const v4i*)&Bw[(nb + rT + i * 16) * 1280 + cT];
    }
    for (int kt = 0; kt < 1280; kt += 128) {
#pragma unroll
        for (int i = 0; i < 4; ++i) {
            *(v4i*)&lA[(rT + i * 16) * 136 + cT] = ra[i];
            *(v4i*)&lB[(rT + i * 16) * 136 + cT] = rb[i];
        }
        __syncthreads();
        if (kt + 128 < 1280) {
#pragma unroll
            for (int i = 0; i < 4; ++i) {
                ra[i] = *(const v4i*)&Aenc[(mb + rT + i * 16) * 1280 + kt + 128 + cT];
                rb[i] = *(const v4i*)&Bw[(nb + rT + i * 16) * 1280 + kt + 128 + cT];
            }
        }
#pragma unroll
        for (int ks = 0; ks < 4; ++ks) {
            v8s a = *(const v8s*)&lA[(w * 16 + (lane & 15)) * 136 + ks * 32 + (lane >> 4) * 8];
#pragma unroll
            for (int f = 0; f < 4; ++f) {
                v8s b = *(const v8s*)&lB[(f * 16 + (lane & 15)) * 136 + ks * 32 + (lane >> 4) * 8];
                acc[f] = __builtin_amdgcn_mfma_f32_16x16x32_bf16(a, b, acc[f], 0, 0, 0);
            }
        }
        __syncthreads();
    }
#pragma unroll
    for (int f = 0; f < 4; ++f) {
        int n = nb + f * 16 + (lane & 15);
        float bs = bias[n];
#pragma unroll
        for (int r = 0; r < 4; ++r) {
            int m = mb + w * 16 + (lane >> 4) * 4 + r;
            Cout[m * 512 + n] = f2bf(acc[f][r] + bs);
        }
    }
}

// ---------------------------------------------------------------------------
// loop_k: 24-step decoder loop. grid = 256 x 256, 47.9 KB LDS (3 blocks/CU
// capacity margin), 1 block/CU in practice. Per step, 3 phases / 3 barriers:
//   A1: blocks 0-63: z emb+h assembly | blocks 64-95: att2 MFMA GEMM
//       (att2 = h @ Wdatt^T + bdatt, 16 cols/block -> att2seq[t], coherent).
//       Replaces round-8's per-block 1MB GEMV (latency-bound ~20us at 4
//       waves/CU) with a 160KB/block MFMA tile.
//   A2: blocks 0-63: scores(att1+att2) + softmax + ctx -> z ctx-cols.
//   B:  all 256: gates[64x16] GEMM with B-operand fed from REGISTERS
//       (wzr[22], 88 VGPRs/thread, preloaded once -> kills the 22MB/step
//       Wz HBM stream and the per-kt HBM-latency stall); LSTM epilogue.
// Rotating z/h/att2 buffers: coherent stores, first-touch cached loads.
// ---------------------------------------------------------------------------
struct SmemGemm {
    unsigned short lA[64 * 264];
    unsigned short lB[16 * 264];
    float gbuf[64 * 20];
};
struct SmemAttn {
    float a2[512];
    float wf[512];
    float es[64];
    float alpha[64];
};
struct LoopSmem {
    union { SmemGemm g; SmemAttn a; } u;     // 47360 B
    unsigned short sm_h[256];                //   512 B
};                                           // 47872 B

__global__ __launch_bounds__(256, 1) void loop_k(
    unsigned short* __restrict__ zseq,        // 24 x [64][2816]
    float* __restrict__ att2seq,              // 24 x [64][512] f32
    const unsigned short* __restrict__ Wdattb, const float* __restrict__ bdatt,
    const unsigned short* __restrict__ att1b, const float* __restrict__ Wfatt,
    const float* __restrict__ bfatt, const unsigned short* __restrict__ encb,
    const unsigned short* __restrict__ embb, const unsigned short* __restrict__ Wzb,
    const float* __restrict__ bz, const float* __restrict__ cst,
    unsigned short* __restrict__ Hallb,
    unsigned short* __restrict__ hseq,        // 25 x [64][1024]; slot 0 = h0
    int* __restrict__ barcnt)
{
    __shared__ LoopSmem sm;
    const int tid = threadIdx.x, lane = tid & 63, w = tid >> 6;
    const int bid = blockIdx.x;          // 0..255
    int ep = 0;

    // ---- Wz slice -> registers (once; ~88 VGPRs). Local B-row lr = tid>>4
    // holds global Wz row (lr&3)*1024 + bid*4 + (lr>>2) (gate=lr&3, hc=lr>>2,
    // matching the epilogue's n = hc*4+gate ... lr = hc*4+gate inverse: the
    // lB content written below is byte-identical to round-8's global-staged
    // version). Thread covers cols kt*256 + (tid&15)*16 .. +16.
    v4i wzr[22];
    {
        const int lr = tid >> 4;
        const size_t gbase = (size_t)((lr & 3) * 1024 + bid * 4 + (lr >> 2)) * 2816
                           + (size_t)((tid & 15) * 16);
#pragma unroll
        for (int kt2 = 0; kt2 < 11; ++kt2) {
            wzr[2 * kt2]     = *(const v4i*)&Wzb[gbase + kt2 * 256];
            wzr[2 * kt2 + 1] = *(const v4i*)&Wzb[gbase + kt2 * 256 + 8];
        }
    }

    // registerized c-state: block bid owns h-cols [bid*4, bid*4+4)
    const int cb = tid >> 2, hc = tid & 3;
    float creg = cst[cb * 1024 + bid * 4 + hc];

    for (int t = 0; t < 24; ++t) {
        unsigned short* zt = zseq + t * 180224;
        float* a2t = att2seq + t * 32768;
        const unsigned short* ht = hseq + t * 65536;

        // ===== A1: z emb+h assembly (blocks 0-63) | att2 GEMM (blocks 64-95)
        if (bid < 64) {
            const int b = bid;
            if (tid < 128) {                                 // z h-columns
                v4i u = *(const v4i*)&ht[b * 1024 + tid * 8];
                cstore4(&zt[b * 2816 + 1792 + tid * 8], u);
            } else if (tid < 192) {                          // z emb-columns
                int t2 = tid - 128;
                v4i u = *(const v4i*)&embb[(b * 24 + t) * 512 + t2 * 8];
                cstore4(&zt[b * 2816 + t2 * 8], u);
            }
        } else if (bid < 96) {
            // att2 tile: C[64, 16 cols at nb] = h[64,1024] @ Wdatt^T + bdatt
            const int nb = (bid - 64) * 16;
            const int rA = tid >> 5, cA = (tid & 31) * 8;
            v4f acc = {0.f, 0.f, 0.f, 0.f};
            v4i ra[8], rb[2];
#pragma unroll
            for (int i = 0; i < 8; ++i)
                ra[i] = *(const v4i*)&ht[(rA + i * 8) * 1024 + cA];
#pragma unroll
            for (int i = 0; i < 2; ++i)
                rb[i] = *(const v4i*)&Wdattb[(size_t)(nb + rA + i * 8) * 1024 + cA];
            for (int kt = 0; kt < 1024; kt += 256) {
#pragma unroll
                for (int i = 0; i < 8; ++i) *(v4i*)&sm.u.g.lA[(rA + i * 8) * 264 + cA] = ra[i];
#pragma unroll
                for (int i = 0; i < 2; ++i) *(v4i*)&sm.u.g.lB[(rA + i * 8) * 264 + cA] = rb[i];
                __syncthreads();
                if (kt + 256 < 1024) {
#pragma unroll
                    for (int i = 0; i < 8; ++i)
                        ra[i] = *(const v4i*)&ht[(rA + i * 8) * 1024 + kt + 256 + cA];
#pragma unroll
                    for (int i = 0; i < 2; ++i)
                        rb[i] = *(const v4i*)&Wdattb[(size_t)(nb + rA + i * 8) * 1024 + kt + 256 + cA];
                }
#pragma unroll
                for (int ks = 0; ks < 8; ++ks) {
                    v8s a = *(const v8s*)&sm.u.g.lA[(w * 16 + (lane & 15)) * 264 + ks * 32 + (lane >> 4) * 8];
                    v8s b = *(const v8s*)&sm.u.g.lB[(lane & 15) * 264 + ks * 32 + (lane >> 4) * 8];
                    acc = __builtin_amdgcn_mfma_f32_16x16x32_bf16(a, b, acc, 0, 0, 0);
                }
                __syncthreads();
            }
            const int n = nb + (lane & 15);
            const float bs = bdatt[n];
#pragma unroll
            for (int r = 0; r < 4; ++r) {
                int m = w * 16 + (lane >> 4) * 4 + r;        // batch index
                cstoreu((unsigned int*)&a2t[m * 512 + n], fbits(acc[r] + bs));
            }
        }
        ++ep; gbar(barcnt, bid, ep);

        // ===== A2: scores + softmax + ctx (blocks 0-63)
        if (bid < 64) {
            const int b = bid;
            float* a2 = sm.u.a.a2; float* wf = sm.u.a.wf;
            float* es = sm.u.a.es; float* alpha = sm.u.a.alpha;
            a2[tid]       = a2t[b * 512 + tid];              // first-touch cached
            a2[tid + 256] = a2t[b * 512 + tid + 256];
            wf[tid]       = Wfatt[tid];
            wf[tid + 256] = Wfatt[tid + 256];
            __syncthreads();
            // scores: one att1 row per wave-iteration
            for (int p = w; p < 49; p += 4) {
                v4i u = *(const v4i*)&att1b[(b * 49 + p) * 512 + lane * 8];
                v4f c0 = *(const v4f*)&a2[lane * 8], c1 = *(const v4f*)&a2[lane * 8 + 4];
                v4f w0 = *(const v4f*)&wf[lane * 8], w1 = *(const v4f*)&wf[lane * 8 + 4];
                float s = 0.f;
#pragma unroll
                for (int q = 0; q < 4; ++q) {
                    unsigned int x = ((unsigned int*)&u)[q];
                    float vlo = lo16(x), vhi = hi16(x);
                    float clo = (q < 2) ? c0[q * 2] : c1[q * 2 - 4];
                    float chi = (q < 2) ? c0[q * 2 + 1] : c1[q * 2 - 3];
                    float wlo = (q < 2) ? w0[q * 2] : w1[q * 2 - 4];
                    float whi = (q < 2) ? w0[q * 2 + 1] : w1[q * 2 - 3];
                    s += fmaxf(vlo + clo, 0.f) * wlo;
                    s += fmaxf(vhi + chi, 0.f) * whi;
                }
#pragma unroll
                for (int off = 32; off > 0; off >>= 1) s += __shfl_xor(s, off);
                if (lane == 0) es[p] = s + bfatt[0];
            }
            __syncthreads();
            if (w == 0) {
                float v = (lane < 49) ? es[lane] : -1e30f;
                float m = v;
#pragma unroll
                for (int off = 32; off > 0; off >>= 1) m = fmaxf(m, __shfl_xor(m, off));
                float e = (lane < 49) ? __expf(v - m) : 0.f;
                float s = e;
#pragma unroll
                for (int off = 32; off > 0; off >>= 1) s += __shfl_xor(s, off);
                if (lane < 49) alpha[lane] = e / s;
            }
            __syncthreads();
            if (tid < 160) {                                 // z ctx-columns
                const int jb = tid * 8;
                float acc[8];
#pragma unroll
                for (int q = 0; q < 8; ++q) acc[q] = 0.f;
                for (int p = 0; p < 49; ++p) {
                    v4i u = *(const v4i*)&encb[(b * 49 + p) * 1280 + jb];
                    float al = alpha[p];
#pragma unroll
                    for (int q = 0; q < 4; ++q) {
                        unsigned int x = ((unsigned int*)&u)[q];
                        acc[2 * q]     += al * lo16(x);
                        acc[2 * q + 1] += al * hi16(x);
                    }
                }
                cstore4(&zt[b * 2816 + 512 + jb], pack8(acc));
            }
        }
        ++ep; gbar(barcnt, bid, ep);

        // ===== B: gates GEMM (B-operand from registers) + LSTM epilogue
        {
            const int hb = bid * 4;
            const int rT = tid >> 5, cT = (tid & 31) * 8;
            const int wrow = (tid >> 4) * 264 + (tid & 15) * 16;
            v4f acc = {0.f, 0.f, 0.f, 0.f};
            v4i ra[8];
#pragma unroll
            for (int i = 0; i < 8; ++i)
                ra[i] = *(const v4i*)&zt[(rT + i * 8) * 2816 + cT];   // cached (L2)
#pragma unroll
            for (int kt2 = 0; kt2 < 11; ++kt2) {
#pragma unroll
                for (int i = 0; i < 8; ++i)
                    *(v4i*)&sm.u.g.lA[(rT + i * 8) * 264 + cT] = ra[i];
                *(v4i*)&sm.u.g.lB[wrow]     = wzr[2 * kt2];
                *(v4i*)&sm.u.g.lB[wrow + 8] = wzr[2 * kt2 + 1];
                __syncthreads();
                if (kt2 < 10) {
#pragma unroll
                    for (int i = 0; i < 8; ++i)
                        ra[i] = *(const v4i*)&zt[(rT + i * 8) * 2816 + (kt2 + 1) * 256 + cT];
                }
#pragma unroll
                for (int ks = 0; ks < 8; ++ks) {
                    v8s a = *(const v8s*)&sm.u.g.lA[(w * 16 + (lane & 15)) * 264 + ks * 32 + (lane >> 4) * 8];
                    v8s b = *(const v8s*)&sm.u.g.lB[(lane & 15) * 264 + ks * 32 + (lane >> 4) * 8];
                    acc = __builtin_amdgcn_mfma_f32_16x16x32_bf16(a, b, acc, 0, 0, 0);
                }
                __syncthreads();
            }
#pragma unroll
            for (int r = 0; r < 4; ++r) {
                int m = w * 16 + (lane >> 4) * 4 + r;   // batch
                int n = lane & 15;                      // local row = hc*4+gate
                sm.u.g.gbuf[m * 20 + n] = acc[r];
            }
            __syncthreads();
            // LSTM epilogue: thread -> (cb, hc); hidx = bid*4 + hc
            {
                const int hidx = hb + hc;
                float gi = sm.u.g.gbuf[cb * 20 + hc * 4 + 0] + bz[hidx];
                float gf = sm.u.g.gbuf[cb * 20 + hc * 4 + 1] + bz[1024 + hidx];
                float gg = sm.u.g.gbuf[cb * 20 + hc * 4 + 2] + bz[2048 + hidx];
                float go = sm.u.g.gbuf[cb * 20 + hc * 4 + 3] + bz[3072 + hidx];
                float cn = sigm(gf) * creg + sigm(gi) * tanhf(gg);
                float hn = sigm(go) * tanhf(cn);
                creg = cn;
                sm.sm_h[tid] = f2bf(hn);
            }
            __syncthreads();
            if (tid < 128) {        // pack 2 bf16 -> dword; coherent h + normal Hall
                unsigned int lo = (unsigned int)sm.sm_h[2 * tid] |
                                  ((unsigned int)sm.sm_h[2 * tid + 1] << 16);
                int b2 = tid >> 1, hco2 = (tid & 1) * 2;
                unsigned int elem = (unsigned int)(b2 * 1024 + hb + hco2);
                cstoreu((unsigned int*)&hseq[(size_t)(t + 1) * 65536 + elem], lo);
                *(unsigned int*)&Hallb[(size_t)t * 65536 + elem] = lo;
            }
        }
        if (t < 23) { ++ep; gbar(barcnt, bid, ep); }
        // final step: kernel completion flushes Hallb before preds_k
    }
}

// ---------------------------------------------------------------------------
// preds: out = Hall[1536,1024](bf16) @ W_out[10000,1024](f32, inline-cvt)^T
// + b_out. Tile 128x128, BK=64, reg-dbuf. grid = 960, XCD-aware mapping.
// ---------------------------------------------------------------------------
__global__ __launch_bounds__(256) void preds_k(
    const unsigned short* __restrict__ Hall, const float* __restrict__ WoutF,
    const float* __restrict__ bout, float* __restrict__ out)
{
    const int bidl = blockIdx.x;
    const int xcd = bidl & 7, loc = bidl >> 3;
    const int nbi = xcd * 10 + loc / 12;
    const int mbi = loc - (loc / 12) * 12;
    if (nbi >= 79) return;
    __shared__ unsigned short lA[128 * 72];
    __shared__ unsigned short lB[128 * 72];
    const int tid = threadIdx.x, lane = tid & 63, w = tid >> 6;
    const int mb = mbi * 128, nb = nbi * 128;
    const int rT = tid >> 3, cT = (tid & 7) * 8;
    v4f acc[2][8];
#pragma unroll
    for (int i = 0; i < 2; ++i)
#pragma unroll
        for (int f = 0; f < 8; ++f) acc[i][f] = (v4f){0.f, 0.f, 0.f, 0.f};
    v4i ra[4];
    v4f rbf[4][2];
#pragma unroll
    for (int i = 0; i < 4; ++i) {
        ra[i] = *(const v4i*)&Hall[(mb + rT + i * 32) * 1024 + cT];
        int n2 = nb + rT + i * 32; if (n2 > 9999) n2 = 9999;
        const float* src = &WoutF[(size_t)n2 * 1024 + cT];
        rbf[i][0] = *(const v4f*)src; rbf[i][1] = *(const v4f*)(src + 4);
    }
    for (int kt = 0; kt < 1024; kt += 64) {
#pragma unroll
        for (int i = 0; i < 4; ++i) {
            *(v4i*)&lA[(rT + i * 32) * 72 + cT] = ra[i];
            *(v4i*)&lB[(rT + i * 32) * 72 + cT] = pack8((const float*)&rbf[i][0]);
        }
        __syncthreads();
        if (kt + 64 < 1024) {
#pragma unroll
            for (int i = 0; i < 4; ++i) {
                ra[i] = *(const v4i*)&Hall[(mb + rT + i * 32) * 1024 + kt + 64 + cT];
                int n2 = nb + rT + i * 32; if (n2 > 9999) n2 = 9999;
                const float* src = &WoutF[(size_t)n2 * 1024 + kt + 64 + cT];
                rbf[i][0] = *(const v4f*)src; rbf[i][1] = *(const v4f*)(src + 4);
            }
        }
#pragma unroll
        for (int ks = 0; ks < 2; ++ks) {
            int ko = ks * 32 + (lane >> 4) * 8;
            v8s a0 = *(const v8s*)&lA[(w * 32 + (lane & 15)) * 72 + ko];
            v8s a1 = *(const v8s*)&lA[(w * 32 + 16 + (lane & 15)) * 72 + ko];
#pragma unroll
            for (int f = 0; f < 8; ++f) {
                v8s b = *(const v8s*)&lB[(f * 16 + (lane & 15)) * 72 + ko];
                acc[0][f] = __builtin_amdgcn_mfma_f32_16x16x32_bf16(a0, b, acc[0][f], 0, 0, 0);
                acc[1][f] = __builtin_amdgcn_mfma_f32_16x16x32_bf16(a1, b, acc[1][f], 0, 0, 0);
            }
        }
        __syncthreads();
    }
#pragma unroll
    for (int f = 0; f < 8; ++f) {
        int n = nb + f * 16 + (lane & 15);
        if (n < 10000) {
            float bs = bout[n];
#pragma unroll
            for (int i = 0; i < 2; ++i)
#pragma unroll
                for (int r = 0; r < 4; ++r) {
                    int m = mb + w * 32 + i * 16 + (lane >> 4) * 4 + r;
                    int tt = m >> 6, bb = m & 63;
                    out[(bb * 24 + tt) * 10000 + n] = acc[i][f][r] + bs;
                }
        }
    }
}

// ---------------------------------------------------------------------------
extern "C" void kernel_launch(void* const* d_in, const int* in_sizes, int n_in,
                              void* d_out, int out_size, void* d_ws, size_t ws_size,
                              hipStream_t stream)
{
    const float* enc   = (const float*)d_in[0];
    const int*   caps  = (const int*)d_in[1];
    const float* embed = (const float*)d_in[2];
    const float* Weatt = (const float*)d_in[3];
    const float* beatt = (const float*)d_in[4];
    const float* Wdatt = (const float*)d_in[5];
    const float* bdatt = (const float*)d_in[6];
    const float* Wfatt = (const float*)d_in[7];
    const float* bfatt = (const float*)d_in[8];
    const float* Wih   = (const float*)d_in[9];
    const float* bih   = (const float*)d_in[10];
    const float* Whh   = (const float*)d_in[11];
    const float* bhh   = (const float*)d_in[12];
    const float* Wh0   = (const float*)d_in[13];
    const float* bh0   = (const float*)d_in[14];
    const float* Wc0   = (const float*)d_in[15];
    const float* bc0   = (const float*)d_in[16];
    const float* WoutF = (const float*)d_in[17];
    const float* bout  = (const float*)d_in[18];
    float* out = (float*)d_out;

    char* ws = (char*)d_ws;
    size_t off = 0;
    auto carve = [&](size_t bytes) -> void* {
        void* p = ws + off; off += (bytes + 255) & ~(size_t)255; return p;
    };
    // total carve ~57 MB (round-7-validated 53.8 + att2seq 3.1)
    unsigned short* Wzb    = (unsigned short*)carve(11534336ull * 2);
    unsigned short* Weattb = (unsigned short*)carve(655360ull * 2);
    unsigned short* Wdattb = (unsigned short*)carve(524288ull * 2);
    unsigned short* encb   = (unsigned short*)carve(4014080ull * 2);
    unsigned short* embb   = (unsigned short*)carve(786432ull * 2);
    unsigned short* meanb  = (unsigned short*)carve(81920ull * 2);
    unsigned short* att1b  = (unsigned short*)carve(1605632ull * 2);
    unsigned short* Hallb  = (unsigned short*)carve(1572864ull * 2);
    unsigned short* zseq   = (unsigned short*)carve(24ull * 180224 * 2);
    unsigned short* hseq   = (unsigned short*)carve(25ull * 65536 * 2);
    float* att2seq = (float*)carve(24ull * 32768 * 4);
    float* bz   = (float*)carve(4096ull * 4);
    float* cst  = (float*)carve(65536ull * 4);
    int*   barcnt = (int*)carve(2048);     // 8 group lines + root + flag

    // barrier counters must be 0 at loop_k entry every iteration
    hipMemsetAsync(barcnt, 0, 2048, stream);

    uber_init<<<8594, 256, 0, stream>>>(Wih, Whh, bih, bhh, Weatt, Wdatt,
        enc, caps, embed, Wzb, Weattb, Wdattb, encb, embb, meanb, bz);

    // h0 -> hseq slot 0 (bf16); c0 -> cst (f32); B read as raw f32
    gemm64_f32B<1><<<64, 256, 0, stream>>>(meanb, 1280, Wh0, 1280, bh0, hseq, 1024);
    gemm64_f32B<0><<<64, 256, 0, stream>>>(meanb, 1280, Wc0, 1280, bc0, cst, 1024);

    gemm_att1_k<<<dim3(8, 49), 256, 0, stream>>>(encb, Weattb, beatt, att1b);

    // 24-step decoder loop: 3 phases / 3 barriers, Wz in registers
    loop_k<<<256, 256, 0, stream>>>(zseq, att2seq, Wdattb, bdatt, att1b, Wfatt,
        bfatt, encb, embb, Wzb, bz, cst, Hallb, hseq, barcnt);

    preds_k<<<960, 256, 0, stream>>>(Hallb, WoutF, bout, out);
}